// Round 6
// baseline (853.406 us; speedup 1.0000x reference)
//
#include <hip/hip_runtime.h>
#include <math.h>

// Problem dims
#define Bb 256
#define Nn 196
#define Dd 512
#define Hh 102
#define Kk 64
#define Mm 40

// ws layout (bytes):
//   [0,            25690112)  logits [B][2][N][K] f32
//   [XH_OFF,  +102760448)     xh [2][B][196][512] bf16   (aggP [2][B][64][512] f32 ALIASES here:
//                              xh is dead after k1; k2 writes aggP, k4 reads it)
//   [XL_OFF,  +102760448)     xl
//   [STATS_OFF, +802816)      stats [2][B][196][2] f32 (mu, rstd)
//   [W1H_OFF, +262144)        w1g_hi [2][128][512] bf16 (g-folded, transposed, j-padded)
//   [W1L_OFF, +262144)        w1g_lo
//   [GWB1_OFF, +2048)         gwb1 [2][128][2] f32 (Gw, B1)
// total ~232.7 MB
#define LOGITS_BYTES 25690112
#define XH_OFF   ((size_t)25690112)
#define XL_OFF   (XH_OFF + 102760448)
#define STATS_OFF (XL_OFF + 102760448)
#define W1H_OFF  (STATS_OFF + 802816)
#define W1L_OFF  (W1H_OFF + 262144)
#define GWB1_OFF (W1L_OFF + 262144)
#define AGG_OFF  XH_OFF

using short8 = __attribute__((ext_vector_type(8))) short;
using f32x4  = __attribute__((ext_vector_type(4))) float;

__device__ __forceinline__ float dot4(const float4 a, const float4 b) {
  return a.x*b.x + a.y*b.y + a.z*b.z + a.w*b.w;
}
__device__ __forceinline__ float4 ld4s(const float* p) { return *(const float4*)p; }
__device__ __forceinline__ float gelu1(float z) {
  return 0.5f * z * (1.f + erff(z * 0.70710678118f));
}
__device__ __forceinline__ unsigned short bf16hi(float v) {
  return (unsigned short)(__float_as_uint(v) >> 16);
}
__device__ __forceinline__ float hipart(float v) {
  return __uint_as_float(__float_as_uint(v) & 0xffff0000u);
}
__device__ __forceinline__ float wave_reduce_sum(float v) {
#pragma unroll
  for (int o = 1; o < 64; o <<= 1) v += __shfl_xor(v, o, 64);
  return v;
}

// ---------------------------------------------------------------------------
// K0w: per path: w1g = g (.) w1, transposed [128 j][512 c], split bf16 hi/lo;
// Gw[j] = sum_c g[c] w1[c,j]; B1[j] = sum_c b[c] w1[c,j] + b1[j]. Pads -> 0.
// ---------------------------------------------------------------------------
__global__ __launch_bounds__(512) void k0_wprep(
    const float* __restrict__ g_s, const float* __restrict__ b_s,
    const float* __restrict__ w1_s, const float* __restrict__ b1_s,
    const float* __restrict__ g_d, const float* __restrict__ b_d,
    const float* __restrict__ w1_d, const float* __restrict__ b1_d,
    unsigned short* __restrict__ w1h, unsigned short* __restrict__ w1l,
    float* __restrict__ gwb1)
{
  const int p = blockIdx.x;
  const float* g  = p ? g_d  : g_s;
  const float* bb = p ? b_d  : b_s;
  const float* w1 = p ? w1_d : w1_s;
  const float* b1 = p ? b1_d : b1_s;
  const int tid = threadIdx.x;

  for (int idx = tid; idx < 128 * 512; idx += 512) {
    const int j = idx & 127, c = idx >> 7;
    const float v = (j < Hh) ? w1[(size_t)c * Hh + j] * g[c] : 0.f;
    w1h[((size_t)(p * 128 + j)) * 512 + c] = bf16hi(v);
    w1l[((size_t)(p * 128 + j)) * 512 + c] = bf16hi(v - hipart(v));
  }

  __shared__ float red[4][128][2];
  const int j = tid & 127, part = tid >> 7;
  float sg = 0.f, sb = 0.f;
  if (j < Hh) {
    for (int c = part * 128; c < part * 128 + 128; ++c) {
      const float w = w1[(size_t)c * Hh + j];
      sg += g[c] * w;
      sb += bb[c] * w;
    }
  }
  red[part][j][0] = sg;
  red[part][j][1] = sb;
  __syncthreads();
  if (part == 0) {
    const float G  = red[0][j][0] + red[1][j][0] + red[2][j][0] + red[3][j][0];
    const float Bv = red[0][j][1] + red[1][j][1] + red[2][j][1] + red[3][j][1];
    gwb1[(p * 128 + j) * 2]     = G;
    gwb1[(p * 128 + j) * 2 + 1] = (j < Hh) ? (Bv + b1[j]) : 0.f;
  }
}

// ---------------------------------------------------------------------------
// K0: one wave per token row: LN stats (mu, rstd) + split raw x -> bf16 hi/lo.
// ---------------------------------------------------------------------------
__global__ __launch_bounds__(256) void k0_split(
    const float* __restrict__ xs, const float* __restrict__ xd,
    float* __restrict__ stats,
    unsigned short* __restrict__ xh, unsigned short* __restrict__ xl)
{
  const int wv = threadIdx.x >> 6, lane = threadIdx.x & 63;
  const int row = blockIdx.x * 4 + wv;            // < 2*256*196 = 100352
  const int p  = row / (Bb * Nn);
  const int rr = row - p * (Bb * Nn);
  const float* src = (p ? xd : xs) + (size_t)rr * Dd + lane * 8;
  const float4 a = ld4s(src);
  const float4 c = ld4s(src + 4);
  float s  = a.x + a.y + a.z + a.w + c.x + c.y + c.z + c.w;
  float ss = dot4(a, a) + dot4(c, c);
  s = wave_reduce_sum(s); ss = wave_reduce_sum(ss);
  const float mu  = s * (1.f / 512.f);
  const float var = fmaxf(ss * (1.f / 512.f) - mu * mu, 0.f);
  const float r   = rsqrtf(var + 1e-5f);
  if (lane == 0) {
    stats[row * 2]     = mu;
    stats[row * 2 + 1] = r;
  }
  short8 hh, ll;
  hh[0] = (short)bf16hi(a.x); ll[0] = (short)bf16hi(a.x - hipart(a.x));
  hh[1] = (short)bf16hi(a.y); ll[1] = (short)bf16hi(a.y - hipart(a.y));
  hh[2] = (short)bf16hi(a.z); ll[2] = (short)bf16hi(a.z - hipart(a.z));
  hh[3] = (short)bf16hi(a.w); ll[3] = (short)bf16hi(a.w - hipart(a.w));
  hh[4] = (short)bf16hi(c.x); ll[4] = (short)bf16hi(c.x - hipart(c.x));
  hh[5] = (short)bf16hi(c.y); ll[5] = (short)bf16hi(c.y - hipart(c.y));
  hh[6] = (short)bf16hi(c.z); ll[6] = (short)bf16hi(c.z - hipart(c.z));
  hh[7] = (short)bf16hi(c.w); ll[7] = (short)bf16hi(c.w - hipart(c.w));
  *(short8*)(xh + (size_t)row * 512 + lane * 8) = hh;
  *(short8*)(xl + (size_t)row * 512 + lane * 8) = ll;
}

// ---------------------------------------------------------------------------
// K1: per 112-token tile of one (b, path). Phase-1: barrier-free MFMA K-loop,
// A/B frags direct from global (split-bf16, 3-product, LN folded into
// epilogue: h = r*S - mu*r*Gw + B1). Phase-2: fp32 logits GEMM via LDS.
// ---------------------------------------------------------------------------
__global__ __launch_bounds__(512) void k1_logits(
    const unsigned short* __restrict__ xh, const unsigned short* __restrict__ xl,
    const float* __restrict__ stats,
    const unsigned short* __restrict__ w1h, const unsigned short* __restrict__ w1l,
    const float* __restrict__ gwb1,
    const float* __restrict__ w2_s, const float* __restrict__ b2_s,
    const float* __restrict__ w2_d, const float* __restrict__ b2_d,
    float* __restrict__ logits)
{
  // hs [112][108] f32 = 12096 | w2t [32][108] = 3456 | st [112][2] = 224
  __shared__ __align__(16) float smem[15776];
  float* hs  = smem;
  float* w2t = smem + 12096;
  float* st  = smem + 15552;

  const int tid = threadIdx.x;
  const int ntile = blockIdx.x, p = blockIdx.y, b = blockIdx.z;
  const int nbase = ntile * 112;
  const float* w2 = p ? w2_d : w2_s;
  const float* b2 = p ? b2_d : b2_s;

  if (tid < 224) {
    const int n = nbase + (tid >> 1);
    st[tid] = (n < Nn) ? stats[((size_t)(p * Bb + b) * Nn + n) * 2 + (tid & 1)] : 0.f;
  }

  const int lane = tid & 63, wv = tid >> 6;
  const int lr = lane & 15, lg = lane >> 4;
  const int jb = wv * 16;
  const size_t xrowbase = ((size_t)(p * Bb + b)) * Nn * 512;
  const unsigned short* wph = w1h + ((size_t)(p * 128 + jb + lr)) * 512 + lg * 8;
  const unsigned short* wpl = w1l + ((size_t)(p * 128 + jb + lr)) * 512 + lg * 8;

  int rowm[7];
#pragma unroll
  for (int m = 0; m < 7; ++m) rowm[m] = min(nbase + m * 16 + lr, Nn - 1);

  f32x4 acc[7];
#pragma unroll
  for (int m = 0; m < 7; ++m) acc[m] = (f32x4){0.f, 0.f, 0.f, 0.f};

#pragma unroll 1
  for (int ch = 0; ch < 16; ++ch) {
    const int co = ch * 32;
    const short8 bh = *(const short8*)(wph + co);
    const short8 bl = *(const short8*)(wpl + co);
#pragma unroll
    for (int m = 0; m < 7; ++m) {
      const size_t off = xrowbase + (size_t)rowm[m] * 512 + lg * 8 + co;
      const short8 ah = *(const short8*)(xh + off);
      const short8 al = *(const short8*)(xl + off);
      acc[m] = __builtin_amdgcn_mfma_f32_16x16x32_bf16(ah, bh, acc[m], 0, 0, 0);
      acc[m] = __builtin_amdgcn_mfma_f32_16x16x32_bf16(ah, bl, acc[m], 0, 0, 0);
      acc[m] = __builtin_amdgcn_mfma_f32_16x16x32_bf16(al, bh, acc[m], 0, 0, 0);
    }
  }

  __syncthreads();   // stats staged; also pre-hs-write sync point

  // epilogue: h = r*S - mu*r*Gw + B1, gelu -> hs. C layout: col=jb+lr, row=m*16+lg*4+rr
  const int col = jb + lr;
  const float Gw = gwb1[(p * 128 + col) * 2];
  const float B1 = gwb1[(p * 128 + col) * 2 + 1];
  if (col < 104) {
#pragma unroll
    for (int m = 0; m < 7; ++m) {
#pragma unroll
      for (int rr = 0; rr < 4; ++rr) {
        const int row = m * 16 + lg * 4 + rr;
        const float mu = st[2 * row], rs = st[2 * row + 1];
        hs[row * 108 + col] = gelu1(rs * acc[m][rr] - mu * rs * Gw + B1);
      }
    }
  }

  // logits GEMM, two k-halves of 32. thread (ki 0..7, ti2 0..63)
  const int ki = tid & 7, ti2 = tid >> 3;
  const int tcl0 = ti2, tcl1 = min(ti2 + 64, 111);
  for (int half = 0; half < 2; ++half) {
    __syncthreads();
    for (int idx = tid; idx < 3264; idx += 512) {
      int j = idx >> 5, ko = idx & 31;
      w2t[ko * 108 + j] = w2[(size_t)j * Kk + half * 32 + ko];
    }
    for (int idx = tid; idx < 192; idx += 512) {
      int ko = idx / 6, jp = 102 + (idx - (idx / 6) * 6);
      w2t[ko * 108 + jp] = 0.f;
    }
    __syncthreads();
    float4 P0 = {0,0,0,0}, P1 = P0;
#pragma unroll 1
    for (int jq = 0; jq < 26; ++jq) {
      const float4 u0 = ld4s(w2t + (ki     ) * 108 + jq * 4);
      const float4 u1 = ld4s(w2t + (ki +  8) * 108 + jq * 4);
      const float4 u2 = ld4s(w2t + (ki + 16) * 108 + jq * 4);
      const float4 u3 = ld4s(w2t + (ki + 24) * 108 + jq * 4);
      const float4 h0 = ld4s(hs + tcl0 * 108 + jq * 4);
      const float4 h1 = ld4s(hs + tcl1 * 108 + jq * 4);
      P0.x += dot4(h0, u0); P0.y += dot4(h0, u1); P0.z += dot4(h0, u2); P0.w += dot4(h0, u3);
      P1.x += dot4(h1, u0); P1.y += dot4(h1, u1); P1.z += dot4(h1, u2); P1.w += dot4(h1, u3);
    }
    {
      const int n0 = nbase + tcl0;
      if (n0 < Nn) {
        float* lg = logits + ((size_t)(b * 2 + p) * Nn + n0) * Kk + half * 32 + ki;
        lg[0]  = P0.x + b2[half * 32 + ki];
        lg[8]  = P0.y + b2[half * 32 + ki + 8];
        lg[16] = P0.z + b2[half * 32 + ki + 16];
        lg[24] = P0.w + b2[half * 32 + ki + 24];
      }
      const int t1 = ti2 + 64;
      const int n1 = nbase + t1;
      if (t1 < 112 && n1 < Nn) {
        float* lg1 = logits + ((size_t)(b * 2 + p) * Nn + n1) * Kk + half * 32 + ki;
        lg1[0]  = P1.x + b2[half * 32 + ki];
        lg1[8]  = P1.y + b2[half * 32 + ki + 8];
        lg1[16] = P1.z + b2[half * 32 + ki + 16];
        lg1[24] = P1.w + b2[half * 32 + ki + 24];
      }
    }
  }
}

// ---------------------------------------------------------------------------
// K2: per (p, b): softmax over n (scale pre-applied), then agg = w @ x
// ---------------------------------------------------------------------------
__global__ __launch_bounds__(512) void k2_softmax_agg(
    const float* __restrict__ x_s, const float* __restrict__ x_d,
    const float* __restrict__ logits, const float* __restrict__ scale,
    float* __restrict__ aggP)
{
  __shared__ __align__(16) float wt[196 * 68];
  __shared__ __align__(16) float xt[4 * 512];
  __shared__ float red[8 * 64];
  __shared__ float mxk[64];
  __shared__ float rsk[64];
  const int tid = threadIdx.x;
  const int p = blockIdx.x, b = blockIdx.y;
  const float* x = p ? x_d : x_s;
  const float sc = scale[0];
  const float* lg = logits + (size_t)(b * 2 + p) * Nn * Kk;
  for (int idx = tid; idx < Nn * Kk; idx += 512) {
    int n = idx >> 6, k = idx & 63;
    wt[n * 68 + k] = lg[idx] * sc;
  }
  __syncthreads();
  const int k = tid & 63, g = tid >> 6;
  float mloc = -1e30f;
  for (int n = g; n < Nn; n += 8) mloc = fmaxf(mloc, wt[n * 68 + k]);
  red[g * 64 + k] = mloc;
  __syncthreads();
  if (g == 0) {
    float mm = red[k];
#pragma unroll
    for (int gg = 1; gg < 8; ++gg) mm = fmaxf(mm, red[gg * 64 + k]);
    mxk[k] = mm;
  }
  __syncthreads();
  const float mk = mxk[k];
  float sloc = 0.f;
  for (int n = g; n < Nn; n += 8) {
    float e = expf(wt[n * 68 + k] - mk);
    wt[n * 68 + k] = e;
    sloc += e;
  }
  red[g * 64 + k] = sloc;
  __syncthreads();
  if (g == 0) {
    float sm = red[k];
#pragma unroll
    for (int gg = 1; gg < 8; ++gg) sm += red[gg * 64 + k];
    rsk[k] = 1.f / sm;
  }
  __syncthreads();
  const float rk = rsk[k];
  for (int n = g; n < Nn; n += 8) wt[n * 68 + k] *= rk;

  // agg: wave kg owns k = kg*8 + kk (kk 0..7); lane cg owns c = cg*4 (+256)
  const int kg = tid >> 6, cg = tid & 63;
  float4 c0a = {0,0,0,0}, c0b = c0a, c1a = c0a, c1b = c0a;
  float4 c2a = c0a, c2b = c0a, c3a = c0a, c3b = c0a;
  float4 c4a = c0a, c4b = c0a, c5a = c0a, c5b = c0a;
  float4 c6a = c0a, c6b = c0a, c7a = c0a, c7b = c0a;

#pragma unroll 1
  for (int nt = 0; nt < 49; ++nt) {
    const int n0 = nt * 4;
    __syncthreads();
    {
      int row = tid >> 7, cf = tid & 127;
      float4 v = ld4s(x + ((size_t)(b * Nn + n0 + row)) * Dd + cf * 4);
      *(float4*)(xt + row * 512 + cf * 4) = v;
    }
    __syncthreads();
#pragma unroll 1
    for (int i = 0; i < 4; ++i) {
      const int n = n0 + i;
      const float4 wa = ld4s(wt + n * 68 + kg * 8);
      const float4 wb = ld4s(wt + n * 68 + kg * 8 + 4);
      const float4 xa = ld4s(xt + i * 512 + cg * 4);
      const float4 xb = ld4s(xt + i * 512 + 256 + cg * 4);
#define KSTEP(W, CA, CB) { \
      (CA).x += (W) * xa.x; (CA).y += (W) * xa.y; (CA).z += (W) * xa.z; (CA).w += (W) * xa.w; \
      (CB).x += (W) * xb.x; (CB).y += (W) * xb.y; (CB).z += (W) * xb.z; (CB).w += (W) * xb.w; }
      KSTEP(wa.x, c0a, c0b) KSTEP(wa.y, c1a, c1b)
      KSTEP(wa.z, c2a, c2b) KSTEP(wa.w, c3a, c3b)
      KSTEP(wb.x, c4a, c4b) KSTEP(wb.y, c5a, c5b)
      KSTEP(wb.z, c6a, c6b) KSTEP(wb.w, c7a, c7b)
#undef KSTEP
    }
  }
#define KOUT(KK, CA, CB) { \
  size_t base = ((size_t)((p * Bb + b) * Kk + kg * 8 + (KK))) * Dd; \
  *(float4*)(aggP + base + cg * 4) = CA; \
  *(float4*)(aggP + base + 256 + cg * 4) = CB; }
  KOUT(0, c0a, c0b) KOUT(1, c1a, c1b) KOUT(2, c2a, c2b) KOUT(3, c3a, c3b)
  KOUT(4, c4a, c4b) KOUT(5, c5a, c5b) KOUT(6, c6a, c6b) KOUT(7, c7a, c7b)
#undef KOUT
}

// ---------------------------------------------------------------------------
// K4: per b: v = l2norm(agg_s+agg_d), t = l2norm(words), sim -> leaky -> pools
// ---------------------------------------------------------------------------
__global__ __launch_bounds__(256) void k4_final(
    const float* __restrict__ words, const float* __restrict__ aggP,
    float* __restrict__ outp)
{
  __shared__ __align__(16) float vsm[16 * 512];
  __shared__ float rnv[16];
  __shared__ float colp[4 * 64];
  __shared__ float rowm[40];
  const int tid = threadIdx.x, b = blockIdx.x;
  const int w = tid >> 6, lane = tid & 63;
  const float* a0 = aggP + (size_t)b * Kk * Dd;
  const float* a1 = aggP + ((size_t)(Bb + b)) * Kk * Dd;
  if (tid < 40) rowm[tid] = -1e30f;
  float cm = -1e30f;

  for (int kc = 0; kc < 4; ++kc) {
    __syncthreads();
    for (int idx = tid; idx < 2048; idx += 256) {
      int r = idx >> 7, cf = idx & 127;
      size_t off = ((size_t)(kc * 16 + r)) * Dd + cf * 4;
      float4 u = ld4s(a0 + off);
      float4 v = ld4s(a1 + off);
      float4 s4 = {u.x + v.x, u.y + v.y, u.z + v.z, u.w + v.w};
      *(float4*)(vsm + r * 512 + cf * 4) = s4;
    }
    __syncthreads();
#pragma unroll
    for (int i = 0; i < 4; ++i) {
      int r = w * 4 + i;
      float4 aq = ld4s(vsm + r * 512 + lane * 4);
      float4 bq = ld4s(vsm + r * 512 + 256 + lane * 4);
      float ss = wave_reduce_sum(dot4(aq, aq) + dot4(bq, bq));
      if (lane == 0) rnv[r] = 1.f / fmaxf(sqrtf(ss), 1e-8f);
    }
    __syncthreads();
    for (int i = 0; i < 10; ++i) {
      const int m = w + 4 * i;
      const float* tr = words + ((size_t)(b * Mm + m)) * Dd;
      float4 ta = ld4s(tr + lane * 4);
      float4 tb = ld4s(tr + 256 + lane * 4);
      float ss = wave_reduce_sum(dot4(ta, ta) + dot4(tb, tb));
      float rnt = 1.f / fmaxf(sqrtf(ss), 1e-8f);
      float rmax_loc = -1e30f;
#pragma unroll 1
      for (int kk = 0; kk < 16; ++kk) {
        float4 va = ld4s(vsm + kk * 512 + lane * 4);
        float4 vb = ld4s(vsm + kk * 512 + 256 + lane * 4);
        float d = wave_reduce_sum(dot4(ta, va) + dot4(tb, vb));
        float s = d * rnt * rnv[kk];
        s = (s >= 0.f) ? s : 0.1f * s;
        rmax_loc = fmaxf(rmax_loc, s);
        if (lane == (kc * 16 + kk)) cm = fmaxf(cm, s);
      }
      if (lane == 0) rowm[m] = fmaxf(rowm[m], rmax_loc);
    }
  }
  colp[w * 64 + lane] = cm;
  __syncthreads();
  if (w == 0) {
    float c2 = fmaxf(fmaxf(colp[lane], colp[64 + lane]),
                     fmaxf(colp[128 + lane], colp[192 + lane]));
    float csum = wave_reduce_sum(c2);
    float rv = (lane < 40) ? rowm[lane] : 0.f;
    float rsum = wave_reduce_sum(rv);
    if (lane == 0) outp[b] = rsum * (1.f / 40.f) + csum * (1.f / 64.f);
  }
}

extern "C" void kernel_launch(void* const* d_in, const int* in_sizes, int n_in,
                              void* d_out, int out_size, void* d_ws, size_t ws_size,
                              hipStream_t stream)
{
  const float* x_s   = (const float*)d_in[0];
  const float* x_d   = (const float*)d_in[1];
  const float* words = (const float*)d_in[2];
  const float* g_s   = (const float*)d_in[3];
  const float* b_s   = (const float*)d_in[4];
  const float* w1_s  = (const float*)d_in[5];
  const float* b1_s  = (const float*)d_in[6];
  const float* w2_s  = (const float*)d_in[7];
  const float* b2_s  = (const float*)d_in[8];
  const float* g_d   = (const float*)d_in[9];
  const float* b_d   = (const float*)d_in[10];
  const float* w1_d  = (const float*)d_in[11];
  const float* b1_d  = (const float*)d_in[12];
  const float* w2_d  = (const float*)d_in[13];
  const float* b2_d  = (const float*)d_in[14];
  const float* scale = (const float*)d_in[15];
  (void)in_sizes; (void)n_in; (void)out_size; (void)ws_size;

  char* ws = (char*)d_ws;
  float* logits          = (float*)ws;
  unsigned short* xh     = (unsigned short*)(ws + XH_OFF);
  unsigned short* xl     = (unsigned short*)(ws + XL_OFF);
  float* stats           = (float*)(ws + STATS_OFF);
  unsigned short* w1h    = (unsigned short*)(ws + W1H_OFF);
  unsigned short* w1l    = (unsigned short*)(ws + W1L_OFF);
  float* gwb1            = (float*)(ws + GWB1_OFF);
  float* aggP            = (float*)(ws + AGG_OFF);   // aliases xh (xh dead after k1)

  hipLaunchKernelGGL(k0_wprep, dim3(2), dim3(512), 0, stream,
                     g_s, b_s, w1_s, b1_s, g_d, b_d, w1_d, b1_d,
                     w1h, w1l, gwb1);
  hipLaunchKernelGGL(k0_split, dim3(25088), dim3(256), 0, stream,
                     x_s, x_d, stats, xh, xl);
  hipLaunchKernelGGL(k1_logits, dim3(2, 2, 256), dim3(512), 0, stream,
                     xh, xl, stats, w1h, w1l, gwb1,
                     w2_s, b2_s, w2_d, b2_d, logits);
  hipLaunchKernelGGL(k2_softmax_agg, dim3(2, 256), dim3(512), 0, stream,
                     x_s, x_d, logits, scale, aggP);
  hipLaunchKernelGGL(k4_final, dim3(256), dim3(256), 0, stream,
                     words, aggP, (float*)d_out);
}

// Round 7
// 685.807 us; speedup vs baseline: 1.2444x; 1.2444x over previous
//
#include <hip/hip_runtime.h>
#include <math.h>

// Problem dims
#define Bb 256
#define Nn 196
#define Dd 512
#define Hh 102
#define Kk 64
#define Mm 40

// ws layout (bytes):
//   [0, 25690112)          logits [B][2][N][K] f32
//   [W1H_OFF, +262144)     w1g_hi [2][128][512] bf16 (g-folded, transposed, j-padded)
//   [W1L_OFF, +262144)     w1g_lo
//   [GWB1_OFF, +2048)      gwb1 [2][128][2] f32 (Gw, B1)
//   [AGG_OFF, +67108864)   aggP [2][B][64][512] f32
// total ~93.3 MB
#define LOGITS_BYTES 25690112
#define W1H_OFF  ((size_t)25690112)
#define W1L_OFF  (W1H_OFF + 262144)
#define GWB1_OFF (W1L_OFF + 262144)
#define AGG_OFF  (GWB1_OFF + 2048)

using short8 = __attribute__((ext_vector_type(8))) short;
using f32x4  = __attribute__((ext_vector_type(4))) float;

__device__ __forceinline__ float dot4(const float4 a, const float4 b) {
  return a.x*b.x + a.y*b.y + a.z*b.z + a.w*b.w;
}
__device__ __forceinline__ float4 ld4s(const float* p) { return *(const float4*)p; }
__device__ __forceinline__ float gelu1(float z) {
  return 0.5f * z * (1.f + erff(z * 0.70710678118f));
}
__device__ __forceinline__ unsigned short bf16hi(float v) {
  return (unsigned short)(__float_as_uint(v) >> 16);
}
__device__ __forceinline__ float hipart(float v) {
  return __uint_as_float(__float_as_uint(v) & 0xffff0000u);
}
__device__ __forceinline__ float wave_reduce_sum(float v) {
#pragma unroll
  for (int o = 1; o < 64; o <<= 1) v += __shfl_xor(v, o, 64);
  return v;
}

// ---------------------------------------------------------------------------
// K0w: grid (2 paths, 8 slices): w1g = g (.) w1 transposed [128 j][512 c],
// split bf16 hi/lo (each slice does 64 c-columns). Slice 0 also computes
// Gw[j] = sum_c g[c] w1[c,j]; B1[j] = sum_c b[c] w1[c,j] + b1[j].
// ---------------------------------------------------------------------------
__global__ __launch_bounds__(512) void k0_wprep(
    const float* __restrict__ g_s, const float* __restrict__ b_s,
    const float* __restrict__ w1_s, const float* __restrict__ b1_s,
    const float* __restrict__ g_d, const float* __restrict__ b_d,
    const float* __restrict__ w1_d, const float* __restrict__ b1_d,
    unsigned short* __restrict__ w1h, unsigned short* __restrict__ w1l,
    float* __restrict__ gwb1)
{
  const int p = blockIdx.x, slice = blockIdx.y;
  const float* g  = p ? g_d  : g_s;
  const float* bb = p ? b_d  : b_s;
  const float* w1 = p ? w1_d : w1_s;
  const float* b1 = p ? b1_d : b1_s;
  const int tid = threadIdx.x;

  for (int idx = slice * 8192 + tid; idx < slice * 8192 + 8192; idx += 512) {
    const int j = idx & 127, c = idx >> 7;
    const float v = (j < Hh) ? w1[(size_t)c * Hh + j] * g[c] : 0.f;
    w1h[((size_t)(p * 128 + j)) * 512 + c] = bf16hi(v);
    w1l[((size_t)(p * 128 + j)) * 512 + c] = bf16hi(v - hipart(v));
  }

  if (slice == 0) {
    __shared__ float red[4][128][2];
    const int j = tid & 127, part = tid >> 7;
    float sg = 0.f, sb = 0.f;
    if (j < Hh) {
      for (int c = part * 128; c < part * 128 + 128; ++c) {
        const float w = w1[(size_t)c * Hh + j];
        sg += g[c] * w;
        sb += bb[c] * w;
      }
    }
    red[part][j][0] = sg;
    red[part][j][1] = sb;
    __syncthreads();
    if (part == 0) {
      const float G  = red[0][j][0] + red[1][j][0] + red[2][j][0] + red[3][j][0];
      const float Bv = red[0][j][1] + red[1][j][1] + red[2][j][1] + red[3][j][1];
      gwb1[(p * 128 + j) * 2]     = G;
      gwb1[(p * 128 + j) * 2 + 1] = (j < Hh) ? (Bv + b1[j]) : 0.f;
    }
  }
}

// ---------------------------------------------------------------------------
// K1: per 112-token tile of one (b, path).
// Stats pre-pass (raw-x mu/rstd -> LDS, one barrier). Phase-1: barrier-free
// MFMA K-loop, A-frags loaded f32 from global + split hi/lo IN REGISTER,
// B-frags from pre-split w1h/w1l (L2-hot). LN folded into epilogue:
// h = rs*S - mu*rs*Gw + B1, then gelu. Phase-2: fp32 logits GEMM via LDS.
// ---------------------------------------------------------------------------
__global__ __launch_bounds__(512) void k1_logits(
    const float* __restrict__ x_s, const float* __restrict__ x_d,
    const unsigned short* __restrict__ w1h, const unsigned short* __restrict__ w1l,
    const float* __restrict__ gwb1,
    const float* __restrict__ w2_s, const float* __restrict__ b2_s,
    const float* __restrict__ w2_d, const float* __restrict__ b2_d,
    float* __restrict__ logits)
{
  // hs [112][108] f32 = 12096 | w2t [32][108] = 3456 | st [112][2] = 224
  __shared__ __align__(16) float smem[15776];
  float* hs  = smem;
  float* w2t = smem + 12096;
  float* st  = smem + 15552;

  const int tid = threadIdx.x;
  const int ntile = blockIdx.x, p = blockIdx.y, b = blockIdx.z;
  const int nbase = ntile * 112;
  const float* x  = p ? x_d : x_s;
  const float* w2 = p ? w2_d : w2_s;
  const float* b2 = p ? b2_d : b2_s;

  // LN stats pre-pass: wave per token, raw-x mu/rstd
  const int wv = tid >> 6, lane = tid & 63;
  for (int i = 0; i < 14; ++i) {
    const int t = wv + 8 * i;
    const int n = nbase + t;
    float s = 0.f, ss = 0.f;
    if (n < Nn) {
      const float* xr = x + ((size_t)(b * Nn + n)) * Dd;
      float4 a = ld4s(xr + lane * 4);
      float4 c = ld4s(xr + 256 + lane * 4);
      s  = a.x + a.y + a.z + a.w + c.x + c.y + c.z + c.w;
      ss = dot4(a, a) + dot4(c, c);
    }
    s = wave_reduce_sum(s); ss = wave_reduce_sum(ss);
    if (lane == 0) {
      float mu  = s * (1.f / 512.f);
      float var = fmaxf(ss * (1.f / 512.f) - mu * mu, 0.f);
      st[2 * t]     = mu;
      st[2 * t + 1] = (n < Nn) ? rsqrtf(var + 1e-5f) : 0.f;
    }
  }
  __syncthreads();

  // phase-1: wave wv owns j-tile jb=16*wv; 7 M-tiles of 16 tokens.
  const int lr = lane & 15, lg = lane >> 4;
  const int jb = wv * 16;
  const unsigned short* wph = w1h + ((size_t)(p * 128 + jb + lr)) * 512 + lg * 8;
  const unsigned short* wpl = w1l + ((size_t)(p * 128 + jb + lr)) * 512 + lg * 8;
  const float* xbase = x + (size_t)b * Nn * Dd + lg * 8;

  size_t roff[7];
#pragma unroll
  for (int m = 0; m < 7; ++m)
    roff[m] = (size_t)min(nbase + m * 16 + lr, Nn - 1) * Dd;

  f32x4 acc[7];
#pragma unroll
  for (int m = 0; m < 7; ++m) acc[m] = (f32x4){0.f, 0.f, 0.f, 0.f};

#pragma unroll 1
  for (int ch = 0; ch < 16; ++ch) {
    const int co = ch * 32;
    const short8 bh = *(const short8*)(wph + co);
    const short8 bl = *(const short8*)(wpl + co);
#pragma unroll
    for (int m = 0; m < 7; ++m) {
      const float* xp = xbase + roff[m] + co;
      const float4 va = ld4s(xp);
      const float4 vb = ld4s(xp + 4);
      short8 ah, al;
      ah[0] = (short)bf16hi(va.x); al[0] = (short)bf16hi(va.x - hipart(va.x));
      ah[1] = (short)bf16hi(va.y); al[1] = (short)bf16hi(va.y - hipart(va.y));
      ah[2] = (short)bf16hi(va.z); al[2] = (short)bf16hi(va.z - hipart(va.z));
      ah[3] = (short)bf16hi(va.w); al[3] = (short)bf16hi(va.w - hipart(va.w));
      ah[4] = (short)bf16hi(vb.x); al[4] = (short)bf16hi(vb.x - hipart(vb.x));
      ah[5] = (short)bf16hi(vb.y); al[5] = (short)bf16hi(vb.y - hipart(vb.y));
      ah[6] = (short)bf16hi(vb.z); al[6] = (short)bf16hi(vb.z - hipart(vb.z));
      ah[7] = (short)bf16hi(vb.w); al[7] = (short)bf16hi(vb.w - hipart(vb.w));
      acc[m] = __builtin_amdgcn_mfma_f32_16x16x32_bf16(ah, bh, acc[m], 0, 0, 0);
      acc[m] = __builtin_amdgcn_mfma_f32_16x16x32_bf16(ah, bl, acc[m], 0, 0, 0);
      acc[m] = __builtin_amdgcn_mfma_f32_16x16x32_bf16(al, bh, acc[m], 0, 0, 0);
    }
  }

  // epilogue: h = rs*S - mu*rs*Gw + B1, gelu -> hs. C: col=jb+lr, row=m*16+lg*4+rr
  const int col = jb + lr;
  const float Gw = gwb1[(p * 128 + col) * 2];
  const float B1 = gwb1[(p * 128 + col) * 2 + 1];
  if (col < 104) {
#pragma unroll
    for (int m = 0; m < 7; ++m) {
#pragma unroll
      for (int rr = 0; rr < 4; ++rr) {
        const int row = m * 16 + lg * 4 + rr;
        const float mu = st[2 * row], rs = st[2 * row + 1];
        hs[row * 108 + col] = gelu1(rs * acc[m][rr] - mu * rs * Gw + B1);
      }
    }
  }

  // logits GEMM, two k-halves of 32. thread (ki 0..7, ti2 0..63)
  const int ki = tid & 7, ti2 = tid >> 3;
  const int tcl0 = ti2, tcl1 = min(ti2 + 64, 111);
  for (int half = 0; half < 2; ++half) {
    __syncthreads();
    for (int idx = tid; idx < 3264; idx += 512) {
      int j = idx >> 5, ko = idx & 31;
      w2t[ko * 108 + j] = w2[(size_t)j * Kk + half * 32 + ko];
    }
    for (int idx = tid; idx < 192; idx += 512) {
      int ko = idx / 6, jp = 102 + (idx - (idx / 6) * 6);
      w2t[ko * 108 + jp] = 0.f;
    }
    __syncthreads();
    float4 P0 = {0,0,0,0}, P1 = P0;
#pragma unroll 1
    for (int jq = 0; jq < 26; ++jq) {
      const float4 u0 = ld4s(w2t + (ki     ) * 108 + jq * 4);
      const float4 u1 = ld4s(w2t + (ki +  8) * 108 + jq * 4);
      const float4 u2 = ld4s(w2t + (ki + 16) * 108 + jq * 4);
      const float4 u3 = ld4s(w2t + (ki + 24) * 108 + jq * 4);
      const float4 h0 = ld4s(hs + tcl0 * 108 + jq * 4);
      const float4 h1 = ld4s(hs + tcl1 * 108 + jq * 4);
      P0.x += dot4(h0, u0); P0.y += dot4(h0, u1); P0.z += dot4(h0, u2); P0.w += dot4(h0, u3);
      P1.x += dot4(h1, u0); P1.y += dot4(h1, u1); P1.z += dot4(h1, u2); P1.w += dot4(h1, u3);
    }
    {
      const int n0 = nbase + tcl0;
      if (n0 < Nn) {
        float* lg = logits + ((size_t)(b * 2 + p) * Nn + n0) * Kk + half * 32 + ki;
        lg[0]  = P0.x + b2[half * 32 + ki];
        lg[8]  = P0.y + b2[half * 32 + ki + 8];
        lg[16] = P0.z + b2[half * 32 + ki + 16];
        lg[24] = P0.w + b2[half * 32 + ki + 24];
      }
      const int t1 = ti2 + 64;
      const int n1 = nbase + t1;
      if (t1 < 112 && n1 < Nn) {
        float* lg1 = logits + ((size_t)(b * 2 + p) * Nn + n1) * Kk + half * 32 + ki;
        lg1[0]  = P1.x + b2[half * 32 + ki];
        lg1[8]  = P1.y + b2[half * 32 + ki + 8];
        lg1[16] = P1.z + b2[half * 32 + ki + 16];
        lg1[24] = P1.w + b2[half * 32 + ki + 24];
      }
    }
  }
}

// ---------------------------------------------------------------------------
// K2: per (p, b): softmax over n (scale pre-applied), then agg = w @ x
// ---------------------------------------------------------------------------
__global__ __launch_bounds__(512) void k2_softmax_agg(
    const float* __restrict__ x_s, const float* __restrict__ x_d,
    const float* __restrict__ logits, const float* __restrict__ scale,
    float* __restrict__ aggP)
{
  __shared__ __align__(16) float wt[196 * 68];
  __shared__ __align__(16) float xt[4 * 512];
  __shared__ float red[8 * 64];
  __shared__ float mxk[64];
  __shared__ float rsk[64];
  const int tid = threadIdx.x;
  const int p = blockIdx.x, b = blockIdx.y;
  const float* x = p ? x_d : x_s;
  const float sc = scale[0];
  const float* lg = logits + (size_t)(b * 2 + p) * Nn * Kk;
  for (int idx = tid; idx < Nn * Kk; idx += 512) {
    int n = idx >> 6, k = idx & 63;
    wt[n * 68 + k] = lg[idx] * sc;
  }
  __syncthreads();
  const int k = tid & 63, g = tid >> 6;
  float mloc = -1e30f;
  for (int n = g; n < Nn; n += 8) mloc = fmaxf(mloc, wt[n * 68 + k]);
  red[g * 64 + k] = mloc;
  __syncthreads();
  if (g == 0) {
    float mm = red[k];
#pragma unroll
    for (int gg = 1; gg < 8; ++gg) mm = fmaxf(mm, red[gg * 64 + k]);
    mxk[k] = mm;
  }
  __syncthreads();
  const float mk = mxk[k];
  float sloc = 0.f;
  for (int n = g; n < Nn; n += 8) {
    float e = expf(wt[n * 68 + k] - mk);
    wt[n * 68 + k] = e;
    sloc += e;
  }
  red[g * 64 + k] = sloc;
  __syncthreads();
  if (g == 0) {
    float sm = red[k];
#pragma unroll
    for (int gg = 1; gg < 8; ++gg) sm += red[gg * 64 + k];
    rsk[k] = 1.f / sm;
  }
  __syncthreads();
  const float rk = rsk[k];
  for (int n = g; n < Nn; n += 8) wt[n * 68 + k] *= rk;

  // agg: wave kg owns k = kg*8 + kk (kk 0..7); lane cg owns c = cg*4 (+256)
  const int kg = tid >> 6, cg = tid & 63;
  float4 c0a = {0,0,0,0}, c0b = c0a, c1a = c0a, c1b = c0a;
  float4 c2a = c0a, c2b = c0a, c3a = c0a, c3b = c0a;
  float4 c4a = c0a, c4b = c0a, c5a = c0a, c5b = c0a;
  float4 c6a = c0a, c6b = c0a, c7a = c0a, c7b = c0a;

#pragma unroll 1
  for (int nt = 0; nt < 49; ++nt) {
    const int n0 = nt * 4;
    __syncthreads();
    {
      int row = tid >> 7, cf = tid & 127;
      float4 v = ld4s(x + ((size_t)(b * Nn + n0 + row)) * Dd + cf * 4);
      *(float4*)(xt + row * 512 + cf * 4) = v;
    }
    __syncthreads();
#pragma unroll 1
    for (int i = 0; i < 4; ++i) {
      const int n = n0 + i;
      const float4 wa = ld4s(wt + n * 68 + kg * 8);
      const float4 wb = ld4s(wt + n * 68 + kg * 8 + 4);
      const float4 xa = ld4s(xt + i * 512 + cg * 4);
      const float4 xb = ld4s(xt + i * 512 + 256 + cg * 4);
#define KSTEP(W, CA, CB) { \
      (CA).x += (W) * xa.x; (CA).y += (W) * xa.y; (CA).z += (W) * xa.z; (CA).w += (W) * xa.w; \
      (CB).x += (W) * xb.x; (CB).y += (W) * xb.y; (CB).z += (W) * xb.z; (CB).w += (W) * xb.w; }
      KSTEP(wa.x, c0a, c0b) KSTEP(wa.y, c1a, c1b)
      KSTEP(wa.z, c2a, c2b) KSTEP(wa.w, c3a, c3b)
      KSTEP(wb.x, c4a, c4b) KSTEP(wb.y, c5a, c5b)
      KSTEP(wb.z, c6a, c6b) KSTEP(wb.w, c7a, c7b)
#undef KSTEP
    }
  }
#define KOUT(KK, CA, CB) { \
  size_t base = ((size_t)((p * Bb + b) * Kk + kg * 8 + (KK))) * Dd; \
  *(float4*)(aggP + base + cg * 4) = CA; \
  *(float4*)(aggP + base + 256 + cg * 4) = CB; }
  KOUT(0, c0a, c0b) KOUT(1, c1a, c1b) KOUT(2, c2a, c2b) KOUT(3, c3a, c3b)
  KOUT(4, c4a, c4b) KOUT(5, c5a, c5b) KOUT(6, c6a, c6b) KOUT(7, c7a, c7b)
#undef KOUT
}

// ---------------------------------------------------------------------------
// K4: per b: v = l2norm(agg_s+agg_d), t = l2norm(words), sim -> leaky -> pools
// ---------------------------------------------------------------------------
__global__ __launch_bounds__(256) void k4_final(
    const float* __restrict__ words, const float* __restrict__ aggP,
    float* __restrict__ outp)
{
  __shared__ __align__(16) float vsm[16 * 512];
  __shared__ float rnv[16];
  __shared__ float colp[4 * 64];
  __shared__ float rowm[40];
  const int tid = threadIdx.x, b = blockIdx.x;
  const int w = tid >> 6, lane = tid & 63;
  const float* a0 = aggP + (size_t)b * Kk * Dd;
  const float* a1 = aggP + ((size_t)(Bb + b)) * Kk * Dd;
  if (tid < 40) rowm[tid] = -1e30f;
  float cm = -1e30f;

  for (int kc = 0; kc < 4; ++kc) {
    __syncthreads();
    for (int idx = tid; idx < 2048; idx += 256) {
      int r = idx >> 7, cf = idx & 127;
      size_t off = ((size_t)(kc * 16 + r)) * Dd + cf * 4;
      float4 u = ld4s(a0 + off);
      float4 v = ld4s(a1 + off);
      float4 s4 = {u.x + v.x, u.y + v.y, u.z + v.z, u.w + v.w};
      *(float4*)(vsm + r * 512 + cf * 4) = s4;
    }
    __syncthreads();
#pragma unroll
    for (int i = 0; i < 4; ++i) {
      int r = w * 4 + i;
      float4 aq = ld4s(vsm + r * 512 + lane * 4);
      float4 bq = ld4s(vsm + r * 512 + 256 + lane * 4);
      float ss = wave_reduce_sum(dot4(aq, aq) + dot4(bq, bq));
      if (lane == 0) rnv[r] = 1.f / fmaxf(sqrtf(ss), 1e-8f);
    }
    __syncthreads();
    for (int i = 0; i < 10; ++i) {
      const int m = w + 4 * i;
      const float* tr = words + ((size_t)(b * Mm + m)) * Dd;
      float4 ta = ld4s(tr + lane * 4);
      float4 tb = ld4s(tr + 256 + lane * 4);
      float ss = wave_reduce_sum(dot4(ta, ta) + dot4(tb, tb));
      float rnt = 1.f / fmaxf(sqrtf(ss), 1e-8f);
      float rmax_loc = -1e30f;
#pragma unroll 1
      for (int kk = 0; kk < 16; ++kk) {
        float4 va = ld4s(vsm + kk * 512 + lane * 4);
        float4 vb = ld4s(vsm + kk * 512 + 256 + lane * 4);
        float d = wave_reduce_sum(dot4(ta, va) + dot4(tb, vb));
        float s = d * rnt * rnv[kk];
        s = (s >= 0.f) ? s : 0.1f * s;
        rmax_loc = fmaxf(rmax_loc, s);
        if (lane == (kc * 16 + kk)) cm = fmaxf(cm, s);
      }
      if (lane == 0) rowm[m] = fmaxf(rowm[m], rmax_loc);
    }
  }
  colp[w * 64 + lane] = cm;
  __syncthreads();
  if (w == 0) {
    float c2 = fmaxf(fmaxf(colp[lane], colp[64 + lane]),
                     fmaxf(colp[128 + lane], colp[192 + lane]));
    float csum = wave_reduce_sum(c2);
    float rv = (lane < 40) ? rowm[lane] : 0.f;
    float rsum = wave_reduce_sum(rv);
    if (lane == 0) outp[b] = rsum * (1.f / 40.f) + csum * (1.f / 64.f);
  }
}

extern "C" void kernel_launch(void* const* d_in, const int* in_sizes, int n_in,
                              void* d_out, int out_size, void* d_ws, size_t ws_size,
                              hipStream_t stream)
{
  const float* x_s   = (const float*)d_in[0];
  const float* x_d   = (const float*)d_in[1];
  const float* words = (const float*)d_in[2];
  const float* g_s   = (const float*)d_in[3];
  const float* b_s   = (const float*)d_in[4];
  const float* w1_s  = (const float*)d_in[5];
  const float* b1_s  = (const float*)d_in[6];
  const float* w2_s  = (const float*)d_in[7];
  const float* b2_s  = (const float*)d_in[8];
  const float* g_d   = (const float*)d_in[9];
  const float* b_d   = (const float*)d_in[10];
  const float* w1_d  = (const float*)d_in[11];
  const float* b1_d  = (const float*)d_in[12];
  const float* w2_d  = (const float*)d_in[13];
  const float* b2_d  = (const float*)d_in[14];
  const float* scale = (const float*)d_in[15];
  (void)in_sizes; (void)n_in; (void)out_size; (void)ws_size;

  char* ws = (char*)d_ws;
  float* logits       = (float*)ws;
  unsigned short* w1h = (unsigned short*)(ws + W1H_OFF);
  unsigned short* w1l = (unsigned short*)(ws + W1L_OFF);
  float* gwb1         = (float*)(ws + GWB1_OFF);
  float* aggP         = (float*)(ws + AGG_OFF);

  hipLaunchKernelGGL(k0_wprep, dim3(2, 8), dim3(512), 0, stream,
                     g_s, b_s, w1_s, b1_s, g_d, b_d, w1_d, b1_d,
                     w1h, w1l, gwb1);
  hipLaunchKernelGGL(k1_logits, dim3(2, 2, 256), dim3(512), 0, stream,
                     x_s, x_d, w1h, w1l, gwb1,
                     w2_s, b2_s, w2_d, b2_d, logits);
  hipLaunchKernelGGL(k2_softmax_agg, dim3(2, 256), dim3(512), 0, stream,
                     x_s, x_d, logits, scale, aggP);
  hipLaunchKernelGGL(k4_final, dim3(256), dim3(256), 0, stream,
                     words, aggP, (float*)d_out);
}

// Round 8
// 493.391 us; speedup vs baseline: 1.7297x; 1.3900x over previous
//
#include <hip/hip_runtime.h>
#include <math.h>

// Problem dims
#define Bb 256
#define Nn 196
#define Dd 512
#define Hh 102
#define Kk 64
#define Mm 40

// ws layout (bytes):
//   [0, 25690112)          logits [B][2][N][K] f32
//   [W1H_OFF, +262144)     w1g_hi [2][128][512] bf16 (g-folded, transposed, j-padded)
//   [W1L_OFF, +262144)     w1g_lo
//   [GWB1_OFF, +2048)      gwb1 [2][128][2] f32 (Gw, B1)
//   [AGG_OFF, +67108864)   aggP [2][B][64][512] f32
// total ~93.3 MB
#define LOGITS_BYTES 25690112
#define W1H_OFF  ((size_t)25690112)
#define W1L_OFF  (W1H_OFF + 262144)
#define GWB1_OFF (W1L_OFF + 262144)
#define AGG_OFF  (GWB1_OFF + 2048)

using short8 = __attribute__((ext_vector_type(8))) short;
using f32x4  = __attribute__((ext_vector_type(4))) float;

__device__ __forceinline__ float dot4(const float4 a, const float4 b) {
  return a.x*b.x + a.y*b.y + a.z*b.z + a.w*b.w;
}
__device__ __forceinline__ float4 ld4s(const float* p) { return *(const float4*)p; }
__device__ __forceinline__ float gelu1(float z) {
  return 0.5f * z * (1.f + erff(z * 0.70710678118f));
}
__device__ __forceinline__ unsigned short bf16hi(float v) {
  return (unsigned short)(__float_as_uint(v) >> 16);
}
__device__ __forceinline__ float hipart(float v) {
  return __uint_as_float(__float_as_uint(v) & 0xffff0000u);
}
__device__ __forceinline__ void split8(const float4 va, const float4 vb,
                                       short8& hh, short8& ll) {
  hh[0] = (short)bf16hi(va.x); ll[0] = (short)bf16hi(va.x - hipart(va.x));
  hh[1] = (short)bf16hi(va.y); ll[1] = (short)bf16hi(va.y - hipart(va.y));
  hh[2] = (short)bf16hi(va.z); ll[2] = (short)bf16hi(va.z - hipart(va.z));
  hh[3] = (short)bf16hi(va.w); ll[3] = (short)bf16hi(va.w - hipart(va.w));
  hh[4] = (short)bf16hi(vb.x); ll[4] = (short)bf16hi(vb.x - hipart(vb.x));
  hh[5] = (short)bf16hi(vb.y); ll[5] = (short)bf16hi(vb.y - hipart(vb.y));
  hh[6] = (short)bf16hi(vb.z); ll[6] = (short)bf16hi(vb.z - hipart(vb.z));
  hh[7] = (short)bf16hi(vb.w); ll[7] = (short)bf16hi(vb.w - hipart(vb.w));
}
__device__ __forceinline__ float wave_reduce_sum(float v) {
#pragma unroll
  for (int o = 1; o < 64; o <<= 1) v += __shfl_xor(v, o, 64);
  return v;
}

// ---------------------------------------------------------------------------
// K0w: grid (2 paths, 8 slices): w1g = g (.) w1 transposed [128 j][512 c],
// split bf16 hi/lo. Slice 0 also computes Gw[j], B1[j].
// ---------------------------------------------------------------------------
__global__ __launch_bounds__(512) void k0_wprep(
    const float* __restrict__ g_s, const float* __restrict__ b_s,
    const float* __restrict__ w1_s, const float* __restrict__ b1_s,
    const float* __restrict__ g_d, const float* __restrict__ b_d,
    const float* __restrict__ w1_d, const float* __restrict__ b1_d,
    unsigned short* __restrict__ w1h, unsigned short* __restrict__ w1l,
    float* __restrict__ gwb1)
{
  const int p = blockIdx.x, slice = blockIdx.y;
  const float* g  = p ? g_d  : g_s;
  const float* bb = p ? b_d  : b_s;
  const float* w1 = p ? w1_d : w1_s;
  const float* b1 = p ? b1_d : b1_s;
  const int tid = threadIdx.x;

  for (int idx = slice * 8192 + tid; idx < slice * 8192 + 8192; idx += 512) {
    const int j = idx & 127, c = idx >> 7;
    const float v = (j < Hh) ? w1[(size_t)c * Hh + j] * g[c] : 0.f;
    w1h[((size_t)(p * 128 + j)) * 512 + c] = bf16hi(v);
    w1l[((size_t)(p * 128 + j)) * 512 + c] = bf16hi(v - hipart(v));
  }

  if (slice == 0) {
    __shared__ float red[4][128][2];
    const int j = tid & 127, part = tid >> 7;
    float sg = 0.f, sb = 0.f;
    if (j < Hh) {
      for (int c = part * 128; c < part * 128 + 128; ++c) {
        const float w = w1[(size_t)c * Hh + j];
        sg += g[c] * w;
        sb += bb[c] * w;
      }
    }
    red[part][j][0] = sg;
    red[part][j][1] = sb;
    __syncthreads();
    if (part == 0) {
      const float G  = red[0][j][0] + red[1][j][0] + red[2][j][0] + red[3][j][0];
      const float Bv = red[0][j][1] + red[1][j][1] + red[2][j][1] + red[3][j][1];
      gwb1[(p * 128 + j) * 2]     = G;
      gwb1[(p * 128 + j) * 2 + 1] = (j < Hh) ? (Bv + b1[j]) : 0.f;
    }
  }
}

// ---------------------------------------------------------------------------
// K1: per 112-token tile of one (b, path).
// Phase-1: double-buffered K-loop (BK=32), ONE barrier/chunk. Staging threads
// (448) load raw x f32, split to bf16 hi/lo into LDS, and accumulate LN
// partial sums on the fly (x read from HBM exactly once). Loads for chunk
// ch+1 issued BEFORE the MFMA cluster on chunk ch (latency hidden); B-frags
// (w1h/w1l, L2-hot) prefetched one chunk ahead in registers. LN folded into
// epilogue: h = rs*S - mu*rs*Gw + B1, gelu. Phase-2: fp32 logits GEMM.
// ---------------------------------------------------------------------------
__global__ __launch_bounds__(512) void k1_logits(
    const float* __restrict__ x_s, const float* __restrict__ x_d,
    const unsigned short* __restrict__ w1h, const unsigned short* __restrict__ w1l,
    const float* __restrict__ gwb1,
    const float* __restrict__ w2_s, const float* __restrict__ b2_s,
    const float* __restrict__ w2_d, const float* __restrict__ b2_d,
    float* __restrict__ logits)
{
  // bytes: [0, 35840) xbuf[2][ hi 8960 | lo 8960 ]  (phase1, aliases hs)
  // floats: hs [0,12096) | part [12096,12992) alias w2t [12096,15552) | st [15552,15776)
  __shared__ __align__(16) float smem[15776];
  float* hs   = smem;
  float* w2t  = smem + 12096;
  float* part = smem + 12096;      // [112][4][2] partial sums (dead before w2t)
  float* st   = smem + 15552;      // [112][2]
  unsigned short* xbuf = (unsigned short*)smem;  // [2][8960] (hi 4480 | lo 4480)

  const int tid = threadIdx.x;
  const int ntile = blockIdx.x, p = blockIdx.y, b = blockIdx.z;
  const int nbase = ntile * 112;
  const float* x  = p ? x_d : x_s;
  const float* w2 = p ? w2_d : w2_s;
  const float* b2 = p ? b2_d : b2_s;

  const int lane = tid & 63, wv = tid >> 6;
  const int lr = lane & 15, lg = lane >> 4;
  const int jb = wv * 16;
  const unsigned short* wph = w1h + ((size_t)(p * 128 + jb + lr)) * 512 + lg * 8;
  const unsigned short* wpl = w1l + ((size_t)(p * 128 + jb + lr)) * 512 + lg * 8;

  // staging thread mapping: t = tid>>2 (row), q = tid&3 (8 cols each)
  const int t = tid >> 2, q = tid & 3;
  const bool stg = (tid < 448);
  const int n = nbase + t;
  const bool valid = stg && (n < Nn);
  const float* xrow = x + ((size_t)(b * Nn + (valid ? n : 0))) * Dd + q * 8;

  float psum = 0.f, psq = 0.f;
  f32x4 acc0 = {0,0,0,0}, acc1 = acc0, acc2 = acc0, acc3 = acc0;
  f32x4 acc4 = acc0, acc5 = acc0, acc6 = acc0;

  // prologue: chunk 0 -> buf 0; B-frags for chunk 0
  short8 bh_c = *(const short8*)(wph);
  short8 bl_c = *(const short8*)(wpl);
  {
    float4 va = {0,0,0,0}, vb = va;
    if (valid) { va = ld4s(xrow); vb = ld4s(xrow + 4); }
    if (stg) {
      psum += va.x + va.y + va.z + va.w + vb.x + vb.y + vb.z + vb.w;
      psq  += dot4(va, va) + dot4(vb, vb);
      short8 hh, ll;
      split8(va, vb, hh, ll);
      *(short8*)(xbuf + t * 40 + q * 8) = hh;
      *(short8*)(xbuf + 4480 + t * 40 + q * 8) = ll;
    }
  }
  __syncthreads();

#pragma unroll 1
  for (int ch = 0; ch < 16; ++ch) {
    const int buf = ch & 1;
    const unsigned short* xh = xbuf + buf * 8960;
    const unsigned short* xl = xh + 4480;

    // issue next chunk's loads BEFORE the MFMA cluster (latency hides under it)
    short8 bh_n = bh_c, bl_n = bl_c;
    float4 va = {0,0,0,0}, vb = va;
    if (ch < 15) {
      const int co = (ch + 1) * 32;
      bh_n = *(const short8*)(wph + co);
      bl_n = *(const short8*)(wpl + co);
      if (valid) { va = ld4s(xrow + co); vb = ld4s(xrow + co + 4); }
    }

    // MFMA cluster on current buffer (ds_read + mfma only)
#define MSTEP(A, M) { \
    const short8 ah = *(const short8*)(xh + ((M) * 16 + lr) * 40 + lg * 8); \
    const short8 al = *(const short8*)(xl + ((M) * 16 + lr) * 40 + lg * 8); \
    (A) = __builtin_amdgcn_mfma_f32_16x16x32_bf16(ah, bh_c, (A), 0, 0, 0); \
    (A) = __builtin_amdgcn_mfma_f32_16x16x32_bf16(ah, bl_c, (A), 0, 0, 0); \
    (A) = __builtin_amdgcn_mfma_f32_16x16x32_bf16(al, bh_c, (A), 0, 0, 0); }
    MSTEP(acc0, 0) MSTEP(acc1, 1) MSTEP(acc2, 2) MSTEP(acc3, 3)
    MSTEP(acc4, 4) MSTEP(acc5, 5) MSTEP(acc6, 6)
#undef MSTEP

    // convert + write next chunk into the other buffer
    if (ch < 15 && stg) {
      psum += va.x + va.y + va.z + va.w + vb.x + vb.y + vb.z + vb.w;
      psq  += dot4(va, va) + dot4(vb, vb);
      short8 hh, ll;
      split8(va, vb, hh, ll);
      unsigned short* xw = xbuf + (buf ^ 1) * 8960;
      *(short8*)(xw + t * 40 + q * 8) = hh;
      *(short8*)(xw + 4480 + t * 40 + q * 8) = ll;
    }
    bh_c = bh_n; bl_c = bl_n;
    __syncthreads();
  }

  // LN stats: reduce 4 partials per row
  if (stg) {
    part[t * 8 + q * 2]     = psum;
    part[t * 8 + q * 2 + 1] = psq;
  }
  __syncthreads();
  if (tid < 112) {
    const float s  = part[tid * 8] + part[tid * 8 + 2] + part[tid * 8 + 4] + part[tid * 8 + 6];
    const float ss = part[tid * 8 + 1] + part[tid * 8 + 3] + part[tid * 8 + 5] + part[tid * 8 + 7];
    const float mu  = s * (1.f / 512.f);
    const float var = fmaxf(ss * (1.f / 512.f) - mu * mu, 0.f);
    st[2 * tid]     = mu;
    st[2 * tid + 1] = rsqrtf(var + 1e-5f);
  }
  __syncthreads();

  // epilogue: h = rs*S - mu*rs*Gw + B1, gelu -> hs. C: col=jb+lr, row=m*16+lg*4+rr
  const int col = jb + lr;
  const float Gw = gwb1[(p * 128 + col) * 2];
  const float B1 = gwb1[(p * 128 + col) * 2 + 1];
  if (col < 104) {
#define EPI(A, M) { \
    _Pragma("unroll") \
    for (int rr = 0; rr < 4; ++rr) { \
      const int row = (M) * 16 + lg * 4 + rr; \
      const float mu = st[2 * row], rs = st[2 * row + 1]; \
      hs[row * 108 + col] = gelu1(rs * (A)[rr] - mu * rs * Gw + B1); \
    } }
    EPI(acc0, 0) EPI(acc1, 1) EPI(acc2, 2) EPI(acc3, 3)
    EPI(acc4, 4) EPI(acc5, 5) EPI(acc6, 6)
#undef EPI
  }

  // logits GEMM, two k-halves of 32. thread (ki 0..7, ti2 0..63)
  const int ki = tid & 7, ti2 = tid >> 3;
  const int tcl0 = ti2, tcl1 = min(ti2 + 64, 111);
  for (int half = 0; half < 2; ++half) {
    __syncthreads();
    for (int idx = tid; idx < 3264; idx += 512) {
      int j = idx >> 5, ko = idx & 31;
      w2t[ko * 108 + j] = w2[(size_t)j * Kk + half * 32 + ko];
    }
    for (int idx = tid; idx < 192; idx += 512) {
      int ko = idx / 6, jp = 102 + (idx - (idx / 6) * 6);
      w2t[ko * 108 + jp] = 0.f;
    }
    __syncthreads();
    float4 P0 = {0,0,0,0}, P1 = P0;
#pragma unroll 1
    for (int jq = 0; jq < 26; ++jq) {
      const float4 u0 = ld4s(w2t + (ki     ) * 108 + jq * 4);
      const float4 u1 = ld4s(w2t + (ki +  8) * 108 + jq * 4);
      const float4 u2 = ld4s(w2t + (ki + 16) * 108 + jq * 4);
      const float4 u3 = ld4s(w2t + (ki + 24) * 108 + jq * 4);
      const float4 h0 = ld4s(hs + tcl0 * 108 + jq * 4);
      const float4 h1 = ld4s(hs + tcl1 * 108 + jq * 4);
      P0.x += dot4(h0, u0); P0.y += dot4(h0, u1); P0.z += dot4(h0, u2); P0.w += dot4(h0, u3);
      P1.x += dot4(h1, u0); P1.y += dot4(h1, u1); P1.z += dot4(h1, u2); P1.w += dot4(h1, u3);
    }
    {
      const int n0 = nbase + tcl0;
      if (n0 < Nn) {
        float* lgp = logits + ((size_t)(b * 2 + p) * Nn + n0) * Kk + half * 32 + ki;
        lgp[0]  = P0.x + b2[half * 32 + ki];
        lgp[8]  = P0.y + b2[half * 32 + ki + 8];
        lgp[16] = P0.z + b2[half * 32 + ki + 16];
        lgp[24] = P0.w + b2[half * 32 + ki + 24];
      }
      const int t1 = ti2 + 64;
      const int n1 = nbase + t1;
      if (t1 < 112 && n1 < Nn) {
        float* lg1 = logits + ((size_t)(b * 2 + p) * Nn + n1) * Kk + half * 32 + ki;
        lg1[0]  = P1.x + b2[half * 32 + ki];
        lg1[8]  = P1.y + b2[half * 32 + ki + 8];
        lg1[16] = P1.z + b2[half * 32 + ki + 16];
        lg1[24] = P1.w + b2[half * 32 + ki + 24];
      }
    }
  }
}

// ---------------------------------------------------------------------------
// K2: per (p, b): softmax over n (scale pre-applied), then agg = w @ x
// ---------------------------------------------------------------------------
__global__ __launch_bounds__(512) void k2_softmax_agg(
    const float* __restrict__ x_s, const float* __restrict__ x_d,
    const float* __restrict__ logits, const float* __restrict__ scale,
    float* __restrict__ aggP)
{
  __shared__ __align__(16) float wt[196 * 68];
  __shared__ __align__(16) float xt[4 * 512];
  __shared__ float red[8 * 64];
  __shared__ float mxk[64];
  __shared__ float rsk[64];
  const int tid = threadIdx.x;
  const int p = blockIdx.x, b = blockIdx.y;
  const float* x = p ? x_d : x_s;
  const float sc = scale[0];
  const float* lg = logits + (size_t)(b * 2 + p) * Nn * Kk;
  for (int idx = tid; idx < Nn * Kk; idx += 512) {
    int n = idx >> 6, k = idx & 63;
    wt[n * 68 + k] = lg[idx] * sc;
  }
  __syncthreads();
  const int k = tid & 63, g = tid >> 6;
  float mloc = -1e30f;
  for (int n = g; n < Nn; n += 8) mloc = fmaxf(mloc, wt[n * 68 + k]);
  red[g * 64 + k] = mloc;
  __syncthreads();
  if (g == 0) {
    float mm = red[k];
#pragma unroll
    for (int gg = 1; gg < 8; ++gg) mm = fmaxf(mm, red[gg * 64 + k]);
    mxk[k] = mm;
  }
  __syncthreads();
  const float mk = mxk[k];
  float sloc = 0.f;
  for (int n = g; n < Nn; n += 8) {
    float e = expf(wt[n * 68 + k] - mk);
    wt[n * 68 + k] = e;
    sloc += e;
  }
  red[g * 64 + k] = sloc;
  __syncthreads();
  if (g == 0) {
    float sm = red[k];
#pragma unroll
    for (int gg = 1; gg < 8; ++gg) sm += red[gg * 64 + k];
    rsk[k] = 1.f / sm;
  }
  __syncthreads();
  const float rk = rsk[k];
  for (int n = g; n < Nn; n += 8) wt[n * 68 + k] *= rk;

  // agg: wave kg owns k = kg*8 + kk (kk 0..7); lane cg owns c = cg*4 (+256)
  const int kg = tid >> 6, cg = tid & 63;
  float4 c0a = {0,0,0,0}, c0b = c0a, c1a = c0a, c1b = c0a;
  float4 c2a = c0a, c2b = c0a, c3a = c0a, c3b = c0a;
  float4 c4a = c0a, c4b = c0a, c5a = c0a, c5b = c0a;
  float4 c6a = c0a, c6b = c0a, c7a = c0a, c7b = c0a;

#pragma unroll 1
  for (int nt = 0; nt < 49; ++nt) {
    const int n0 = nt * 4;
    __syncthreads();
    {
      int row = tid >> 7, cf = tid & 127;
      float4 v = ld4s(x + ((size_t)(b * Nn + n0 + row)) * Dd + cf * 4);
      *(float4*)(xt + row * 512 + cf * 4) = v;
    }
    __syncthreads();
#pragma unroll 1
    for (int i = 0; i < 4; ++i) {
      const int n = n0 + i;
      const float4 wa = ld4s(wt + n * 68 + kg * 8);
      const float4 wb = ld4s(wt + n * 68 + kg * 8 + 4);
      const float4 xa = ld4s(xt + i * 512 + cg * 4);
      const float4 xb = ld4s(xt + i * 512 + 256 + cg * 4);
#define KSTEP(W, CA, CB) { \
      (CA).x += (W) * xa.x; (CA).y += (W) * xa.y; (CA).z += (W) * xa.z; (CA).w += (W) * xa.w; \
      (CB).x += (W) * xb.x; (CB).y += (W) * xb.y; (CB).z += (W) * xb.z; (CB).w += (W) * xb.w; }
      KSTEP(wa.x, c0a, c0b) KSTEP(wa.y, c1a, c1b)
      KSTEP(wa.z, c2a, c2b) KSTEP(wa.w, c3a, c3b)
      KSTEP(wb.x, c4a, c4b) KSTEP(wb.y, c5a, c5b)
      KSTEP(wb.z, c6a, c6b) KSTEP(wb.w, c7a, c7b)
#undef KSTEP
    }
  }
#define KOUT(KK, CA, CB) { \
  size_t base = ((size_t)((p * Bb + b) * Kk + kg * 8 + (KK))) * Dd; \
  *(float4*)(aggP + base + cg * 4) = CA; \
  *(float4*)(aggP + base + 256 + cg * 4) = CB; }
  KOUT(0, c0a, c0b) KOUT(1, c1a, c1b) KOUT(2, c2a, c2b) KOUT(3, c3a, c3b)
  KOUT(4, c4a, c4b) KOUT(5, c5a, c5b) KOUT(6, c6a, c6b) KOUT(7, c7a, c7b)
#undef KOUT
}

// ---------------------------------------------------------------------------
// K4: per b: v = l2norm(agg_s+agg_d), t = l2norm(words), sim -> leaky -> pools
// ---------------------------------------------------------------------------
__global__ __launch_bounds__(256) void k4_final(
    const float* __restrict__ words, const float* __restrict__ aggP,
    float* __restrict__ outp)
{
  __shared__ __align__(16) float vsm[16 * 512];
  __shared__ float rnv[16];
  __shared__ float colp[4 * 64];
  __shared__ float rowm[40];
  const int tid = threadIdx.x, b = blockIdx.x;
  const int w = tid >> 6, lane = tid & 63;
  const float* a0 = aggP + (size_t)b * Kk * Dd;
  const float* a1 = aggP + ((size_t)(Bb + b)) * Kk * Dd;
  if (tid < 40) rowm[tid] = -1e30f;
  float cm = -1e30f;

  for (int kc = 0; kc < 4; ++kc) {
    __syncthreads();
    for (int idx = tid; idx < 2048; idx += 256) {
      int r = idx >> 7, cf = idx & 127;
      size_t off = ((size_t)(kc * 16 + r)) * Dd + cf * 4;
      float4 u = ld4s(a0 + off);
      float4 v = ld4s(a1 + off);
      float4 s4 = {u.x + v.x, u.y + v.y, u.z + v.z, u.w + v.w};
      *(float4*)(vsm + r * 512 + cf * 4) = s4;
    }
    __syncthreads();
#pragma unroll
    for (int i = 0; i < 4; ++i) {
      int r = w * 4 + i;
      float4 aq = ld4s(vsm + r * 512 + lane * 4);
      float4 bq = ld4s(vsm + r * 512 + 256 + lane * 4);
      float ss = wave_reduce_sum(dot4(aq, aq) + dot4(bq, bq));
      if (lane == 0) rnv[r] = 1.f / fmaxf(sqrtf(ss), 1e-8f);
    }
    __syncthreads();
    for (int i = 0; i < 10; ++i) {
      const int m = w + 4 * i;
      const float* tr = words + ((size_t)(b * Mm + m)) * Dd;
      float4 ta = ld4s(tr + lane * 4);
      float4 tb = ld4s(tr + 256 + lane * 4);
      float ss = wave_reduce_sum(dot4(ta, ta) + dot4(tb, tb));
      float rnt = 1.f / fmaxf(sqrtf(ss), 1e-8f);
      float rmax_loc = -1e30f;
#pragma unroll 1
      for (int kk = 0; kk < 16; ++kk) {
        float4 va = ld4s(vsm + kk * 512 + lane * 4);
        float4 vb = ld4s(vsm + kk * 512 + 256 + lane * 4);
        float d = wave_reduce_sum(dot4(ta, va) + dot4(tb, vb));
        float s = d * rnt * rnv[kk];
        s = (s >= 0.f) ? s : 0.1f * s;
        rmax_loc = fmaxf(rmax_loc, s);
        if (lane == (kc * 16 + kk)) cm = fmaxf(cm, s);
      }
      if (lane == 0) rowm[m] = fmaxf(rowm[m], rmax_loc);
    }
  }
  colp[w * 64 + lane] = cm;
  __syncthreads();
  if (w == 0) {
    float c2 = fmaxf(fmaxf(colp[lane], colp[64 + lane]),
                     fmaxf(colp[128 + lane], colp[192 + lane]));
    float csum = wave_reduce_sum(c2);
    float rv = (lane < 40) ? rowm[lane] : 0.f;
    float rsum = wave_reduce_sum(rv);
    if (lane == 0) outp[b] = rsum * (1.f / 40.f) + csum * (1.f / 64.f);
  }
}

extern "C" void kernel_launch(void* const* d_in, const int* in_sizes, int n_in,
                              void* d_out, int out_size, void* d_ws, size_t ws_size,
                              hipStream_t stream)
{
  const float* x_s   = (const float*)d_in[0];
  const float* x_d   = (const float*)d_in[1];
  const float* words = (const float*)d_in[2];
  const float* g_s   = (const float*)d_in[3];
  const float* b_s   = (const float*)d_in[4];
  const float* w1_s  = (const float*)d_in[5];
  const float* b1_s  = (const float*)d_in[6];
  const float* w2_s  = (const float*)d_in[7];
  const float* b2_s  = (const float*)d_in[8];
  const float* g_d   = (const float*)d_in[9];
  const float* b_d   = (const float*)d_in[10];
  const float* w1_d  = (const float*)d_in[11];
  const float* b1_d  = (const float*)d_in[12];
  const float* w2_d  = (const float*)d_in[13];
  const float* b2_d  = (const float*)d_in[14];
  const float* scale = (const float*)d_in[15];
  (void)in_sizes; (void)n_in; (void)out_size; (void)ws_size;

  char* ws = (char*)d_ws;
  float* logits       = (float*)ws;
  unsigned short* w1h = (unsigned short*)(ws + W1H_OFF);
  unsigned short* w1l = (unsigned short*)(ws + W1L_OFF);
  float* gwb1         = (float*)(ws + GWB1_OFF);
  float* aggP         = (float*)(ws + AGG_OFF);

  hipLaunchKernelGGL(k0_wprep, dim3(2, 8), dim3(512), 0, stream,
                     g_s, b_s, w1_s, b1_s, g_d, b_d, w1_d, b1_d,
                     w1h, w1l, gwb1);
  hipLaunchKernelGGL(k1_logits, dim3(2, 2, 256), dim3(512), 0, stream,
                     x_s, x_d, w1h, w1l, gwb1,
                     w2_s, b2_s, w2_d, b2_d, logits);
  hipLaunchKernelGGL(k2_softmax_agg, dim3(2, 256), dim3(512), 0, stream,
                     x_s, x_d, logits, scale, aggP);
  hipLaunchKernelGGL(k4_final, dim3(256), dim3(256), 0, stream,
                     words, aggP, (float*)d_out);
}

// Round 9
// 332.805 us; speedup vs baseline: 2.5643x; 1.4825x over previous
//
#include <hip/hip_runtime.h>
#include <math.h>

// Problem dims
#define Bb 256
#define Nn 196
#define Dd 512
#define Hh 102
#define Kk 64
#define Mm 40

// ws layout (bytes):
//   [0, 25690112)          logits [B][2][N][K] f32
//   [W1H_OFF, +262144)     w1g_hi [2][128][512] bf16 (g-folded, transposed, j-padded)
//   [W1L_OFF, +262144)     w1g_lo
//   [GWB1_OFF, +2048)      gwb1 [2][128][2] f32 (Gw, B1)
//   [AGG_OFF, +67108864)   aggP [2][B][64][512] f32
// total ~93.3 MB
#define LOGITS_BYTES 25690112
#define W1H_OFF  ((size_t)25690112)
#define W1L_OFF  (W1H_OFF + 262144)
#define GWB1_OFF (W1L_OFF + 262144)
#define AGG_OFF  (GWB1_OFF + 2048)

using short8 = __attribute__((ext_vector_type(8))) short;
using f32x4  = __attribute__((ext_vector_type(4))) float;

__device__ __forceinline__ float dot4(const float4 a, const float4 b) {
  return a.x*b.x + a.y*b.y + a.z*b.z + a.w*b.w;
}
__device__ __forceinline__ float4 ld4s(const float* p) { return *(const float4*)p; }
__device__ __forceinline__ float gelu1(float z) {
  return 0.5f * z * (1.f + erff(z * 0.70710678118f));
}
__device__ __forceinline__ unsigned short bf16hi(float v) {
  return (unsigned short)(__float_as_uint(v) >> 16);
}
__device__ __forceinline__ float hipart(float v) {
  return __uint_as_float(__float_as_uint(v) & 0xffff0000u);
}
__device__ __forceinline__ void split8(const float4 va, const float4 vb,
                                       short8& hh, short8& ll) {
  hh[0] = (short)bf16hi(va.x); ll[0] = (short)bf16hi(va.x - hipart(va.x));
  hh[1] = (short)bf16hi(va.y); ll[1] = (short)bf16hi(va.y - hipart(va.y));
  hh[2] = (short)bf16hi(va.z); ll[2] = (short)bf16hi(va.z - hipart(va.z));
  hh[3] = (short)bf16hi(va.w); ll[3] = (short)bf16hi(va.w - hipart(va.w));
  hh[4] = (short)bf16hi(vb.x); ll[4] = (short)bf16hi(vb.x - hipart(vb.x));
  hh[5] = (short)bf16hi(vb.y); ll[5] = (short)bf16hi(vb.y - hipart(vb.y));
  hh[6] = (short)bf16hi(vb.z); ll[6] = (short)bf16hi(vb.z - hipart(vb.z));
  hh[7] = (short)bf16hi(vb.w); ll[7] = (short)bf16hi(vb.w - hipart(vb.w));
}
__device__ __forceinline__ float wave_reduce_sum(float v) {
#pragma unroll
  for (int o = 1; o < 64; o <<= 1) v += __shfl_xor(v, o, 64);
  return v;
}
__device__ __forceinline__ float wave_reduce_max(float v) {
#pragma unroll
  for (int o = 1; o < 64; o <<= 1) v = fmaxf(v, __shfl_xor(v, o, 64));
  return v;
}

// ---------------------------------------------------------------------------
// K0w: grid (2 paths, 8 slices): w1g = g (.) w1 transposed [128 j][512 c],
// split bf16 hi/lo. Slice 0 also computes Gw[j], B1[j].
// ---------------------------------------------------------------------------
__global__ __launch_bounds__(512) void k0_wprep(
    const float* __restrict__ g_s, const float* __restrict__ b_s,
    const float* __restrict__ w1_s, const float* __restrict__ b1_s,
    const float* __restrict__ g_d, const float* __restrict__ b_d,
    const float* __restrict__ w1_d, const float* __restrict__ b1_d,
    unsigned short* __restrict__ w1h, unsigned short* __restrict__ w1l,
    float* __restrict__ gwb1)
{
  const int p = blockIdx.x, slice = blockIdx.y;
  const float* g  = p ? g_d  : g_s;
  const float* bb = p ? b_d  : b_s;
  const float* w1 = p ? w1_d : w1_s;
  const float* b1 = p ? b1_d : b1_s;
  const int tid = threadIdx.x;

  for (int idx = slice * 8192 + tid; idx < slice * 8192 + 8192; idx += 512) {
    const int j = idx & 127, c = idx >> 7;
    const float v = (j < Hh) ? w1[(size_t)c * Hh + j] * g[c] : 0.f;
    w1h[((size_t)(p * 128 + j)) * 512 + c] = bf16hi(v);
    w1l[((size_t)(p * 128 + j)) * 512 + c] = bf16hi(v - hipart(v));
  }

  if (slice == 0) {
    __shared__ float red[4][128][2];
    const int j = tid & 127, part = tid >> 7;
    float sg = 0.f, sb = 0.f;
    if (j < Hh) {
      for (int c = part * 128; c < part * 128 + 128; ++c) {
        const float w = w1[(size_t)c * Hh + j];
        sg += g[c] * w;
        sb += bb[c] * w;
      }
    }
    red[part][j][0] = sg;
    red[part][j][1] = sb;
    __syncthreads();
    if (part == 0) {
      const float G  = red[0][j][0] + red[1][j][0] + red[2][j][0] + red[3][j][0];
      const float Bv = red[0][j][1] + red[1][j][1] + red[2][j][1] + red[3][j][1];
      gwb1[(p * 128 + j) * 2]     = G;
      gwb1[(p * 128 + j) * 2 + 1] = (j < Hh) ? (Bv + b1[j]) : 0.f;
    }
  }
}

// ---------------------------------------------------------------------------
// K1: per 112-token tile of one (b, path). Double-buffered split-bf16 MFMA
// K-loop with in-flight staging; LN folded into epilogue. (unchanged r7)
// ---------------------------------------------------------------------------
__global__ __launch_bounds__(512) void k1_logits(
    const float* __restrict__ x_s, const float* __restrict__ x_d,
    const unsigned short* __restrict__ w1h, const unsigned short* __restrict__ w1l,
    const float* __restrict__ gwb1,
    const float* __restrict__ w2_s, const float* __restrict__ b2_s,
    const float* __restrict__ w2_d, const float* __restrict__ b2_d,
    float* __restrict__ logits)
{
  __shared__ __align__(16) float smem[15776];
  float* hs   = smem;
  float* w2t  = smem + 12096;
  float* part = smem + 12096;
  float* st   = smem + 15552;
  unsigned short* xbuf = (unsigned short*)smem;

  const int tid = threadIdx.x;
  const int ntile = blockIdx.x, p = blockIdx.y, b = blockIdx.z;
  const int nbase = ntile * 112;
  const float* x  = p ? x_d : x_s;
  const float* w2 = p ? w2_d : w2_s;
  const float* b2 = p ? b2_d : b2_s;

  const int lane = tid & 63, wv = tid >> 6;
  const int lr = lane & 15, lg = lane >> 4;
  const int jb = wv * 16;
  const unsigned short* wph = w1h + ((size_t)(p * 128 + jb + lr)) * 512 + lg * 8;
  const unsigned short* wpl = w1l + ((size_t)(p * 128 + jb + lr)) * 512 + lg * 8;

  const int t = tid >> 2, q = tid & 3;
  const bool stg = (tid < 448);
  const int n = nbase + t;
  const bool valid = stg && (n < Nn);
  const float* xrow = x + ((size_t)(b * Nn + (valid ? n : 0))) * Dd + q * 8;

  float psum = 0.f, psq = 0.f;
  f32x4 acc0 = {0,0,0,0}, acc1 = acc0, acc2 = acc0, acc3 = acc0;
  f32x4 acc4 = acc0, acc5 = acc0, acc6 = acc0;

  short8 bh_c = *(const short8*)(wph);
  short8 bl_c = *(const short8*)(wpl);
  {
    float4 va = {0,0,0,0}, vb = va;
    if (valid) { va = ld4s(xrow); vb = ld4s(xrow + 4); }
    if (stg) {
      psum += va.x + va.y + va.z + va.w + vb.x + vb.y + vb.z + vb.w;
      psq  += dot4(va, va) + dot4(vb, vb);
      short8 hh, ll;
      split8(va, vb, hh, ll);
      *(short8*)(xbuf + t * 40 + q * 8) = hh;
      *(short8*)(xbuf + 4480 + t * 40 + q * 8) = ll;
    }
  }
  __syncthreads();

#pragma unroll 1
  for (int ch = 0; ch < 16; ++ch) {
    const int buf = ch & 1;
    const unsigned short* xh = xbuf + buf * 8960;
    const unsigned short* xl = xh + 4480;

    short8 bh_n = bh_c, bl_n = bl_c;
    float4 va = {0,0,0,0}, vb = va;
    if (ch < 15) {
      const int co = (ch + 1) * 32;
      bh_n = *(const short8*)(wph + co);
      bl_n = *(const short8*)(wpl + co);
      if (valid) { va = ld4s(xrow + co); vb = ld4s(xrow + co + 4); }
    }

#define MSTEP(A, M) { \
    const short8 ah = *(const short8*)(xh + ((M) * 16 + lr) * 40 + lg * 8); \
    const short8 al = *(const short8*)(xl + ((M) * 16 + lr) * 40 + lg * 8); \
    (A) = __builtin_amdgcn_mfma_f32_16x16x32_bf16(ah, bh_c, (A), 0, 0, 0); \
    (A) = __builtin_amdgcn_mfma_f32_16x16x32_bf16(ah, bl_c, (A), 0, 0, 0); \
    (A) = __builtin_amdgcn_mfma_f32_16x16x32_bf16(al, bh_c, (A), 0, 0, 0); }
    MSTEP(acc0, 0) MSTEP(acc1, 1) MSTEP(acc2, 2) MSTEP(acc3, 3)
    MSTEP(acc4, 4) MSTEP(acc5, 5) MSTEP(acc6, 6)
#undef MSTEP

    if (ch < 15 && stg) {
      psum += va.x + va.y + va.z + va.w + vb.x + vb.y + vb.z + vb.w;
      psq  += dot4(va, va) + dot4(vb, vb);
      short8 hh, ll;
      split8(va, vb, hh, ll);
      unsigned short* xw = xbuf + (buf ^ 1) * 8960;
      *(short8*)(xw + t * 40 + q * 8) = hh;
      *(short8*)(xw + 4480 + t * 40 + q * 8) = ll;
    }
    bh_c = bh_n; bl_c = bl_n;
    __syncthreads();
  }

  if (stg) {
    part[t * 8 + q * 2]     = psum;
    part[t * 8 + q * 2 + 1] = psq;
  }
  __syncthreads();
  if (tid < 112) {
    const float s  = part[tid * 8] + part[tid * 8 + 2] + part[tid * 8 + 4] + part[tid * 8 + 6];
    const float ss = part[tid * 8 + 1] + part[tid * 8 + 3] + part[tid * 8 + 5] + part[tid * 8 + 7];
    const float mu  = s * (1.f / 512.f);
    const float var = fmaxf(ss * (1.f / 512.f) - mu * mu, 0.f);
    st[2 * tid]     = mu;
    st[2 * tid + 1] = rsqrtf(var + 1e-5f);
  }
  __syncthreads();

  const int col = jb + lr;
  const float Gw = gwb1[(p * 128 + col) * 2];
  const float B1 = gwb1[(p * 128 + col) * 2 + 1];
  if (col < 104) {
#define EPI(A, M) { \
    _Pragma("unroll") \
    for (int rr = 0; rr < 4; ++rr) { \
      const int row = (M) * 16 + lg * 4 + rr; \
      const float mu = st[2 * row], rs = st[2 * row + 1]; \
      hs[row * 108 + col] = gelu1(rs * (A)[rr] - mu * rs * Gw + B1); \
    } }
    EPI(acc0, 0) EPI(acc1, 1) EPI(acc2, 2) EPI(acc3, 3)
    EPI(acc4, 4) EPI(acc5, 5) EPI(acc6, 6)
#undef EPI
  }

  const int ki = tid & 7, ti2 = tid >> 3;
  const int tcl0 = ti2, tcl1 = min(ti2 + 64, 111);
  for (int half = 0; half < 2; ++half) {
    __syncthreads();
    for (int idx = tid; idx < 3264; idx += 512) {
      int j = idx >> 5, ko = idx & 31;
      w2t[ko * 108 + j] = w2[(size_t)j * Kk + half * 32 + ko];
    }
    for (int idx = tid; idx < 192; idx += 512) {
      int ko = idx / 6, jp = 102 + (idx - (idx / 6) * 6);
      w2t[ko * 108 + jp] = 0.f;
    }
    __syncthreads();
    float4 P0 = {0,0,0,0}, P1 = P0;
#pragma unroll 1
    for (int jq = 0; jq < 26; ++jq) {
      const float4 u0 = ld4s(w2t + (ki     ) * 108 + jq * 4);
      const float4 u1 = ld4s(w2t + (ki +  8) * 108 + jq * 4);
      const float4 u2 = ld4s(w2t + (ki + 16) * 108 + jq * 4);
      const float4 u3 = ld4s(w2t + (ki + 24) * 108 + jq * 4);
      const float4 h0 = ld4s(hs + tcl0 * 108 + jq * 4);
      const float4 h1 = ld4s(hs + tcl1 * 108 + jq * 4);
      P0.x += dot4(h0, u0); P0.y += dot4(h0, u1); P0.z += dot4(h0, u2); P0.w += dot4(h0, u3);
      P1.x += dot4(h1, u0); P1.y += dot4(h1, u1); P1.z += dot4(h1, u2); P1.w += dot4(h1, u3);
    }
    {
      const int n0 = nbase + tcl0;
      if (n0 < Nn) {
        float* lgp = logits + ((size_t)(b * 2 + p) * Nn + n0) * Kk + half * 32 + ki;
        lgp[0]  = P0.x + b2[half * 32 + ki];
        lgp[8]  = P0.y + b2[half * 32 + ki + 8];
        lgp[16] = P0.z + b2[half * 32 + ki + 16];
        lgp[24] = P0.w + b2[half * 32 + ki + 24];
      }
      const int t1 = ti2 + 64;
      const int n1 = nbase + t1;
      if (t1 < 112 && n1 < Nn) {
        float* lg1 = logits + ((size_t)(b * 2 + p) * Nn + n1) * Kk + half * 32 + ki;
        lg1[0]  = P1.x + b2[half * 32 + ki];
        lg1[8]  = P1.y + b2[half * 32 + ki + 8];
        lg1[16] = P1.z + b2[half * 32 + ki + 16];
        lg1[24] = P1.w + b2[half * 32 + ki + 24];
      }
    }
  }
}

// ---------------------------------------------------------------------------
// K2: per (p, b): softmax over n (scale pre-applied), then agg = w @ x
// ---------------------------------------------------------------------------
__global__ __launch_bounds__(512) void k2_softmax_agg(
    const float* __restrict__ x_s, const float* __restrict__ x_d,
    const float* __restrict__ logits, const float* __restrict__ scale,
    float* __restrict__ aggP)
{
  __shared__ __align__(16) float wt[196 * 68];
  __shared__ __align__(16) float xt[4 * 512];
  __shared__ float red[8 * 64];
  __shared__ float mxk[64];
  __shared__ float rsk[64];
  const int tid = threadIdx.x;
  const int p = blockIdx.x, b = blockIdx.y;
  const float* x = p ? x_d : x_s;
  const float sc = scale[0];
  const float* lg = logits + (size_t)(b * 2 + p) * Nn * Kk;
  for (int idx = tid; idx < Nn * Kk; idx += 512) {
    int n = idx >> 6, k = idx & 63;
    wt[n * 68 + k] = lg[idx] * sc;
  }
  __syncthreads();
  const int k = tid & 63, g = tid >> 6;
  float mloc = -1e30f;
  for (int n = g; n < Nn; n += 8) mloc = fmaxf(mloc, wt[n * 68 + k]);
  red[g * 64 + k] = mloc;
  __syncthreads();
  if (g == 0) {
    float mm = red[k];
#pragma unroll
    for (int gg = 1; gg < 8; ++gg) mm = fmaxf(mm, red[gg * 64 + k]);
    mxk[k] = mm;
  }
  __syncthreads();
  const float mk = mxk[k];
  float sloc = 0.f;
  for (int n = g; n < Nn; n += 8) {
    float e = expf(wt[n * 68 + k] - mk);
    wt[n * 68 + k] = e;
    sloc += e;
  }
  red[g * 64 + k] = sloc;
  __syncthreads();
  if (g == 0) {
    float sm = red[k];
#pragma unroll
    for (int gg = 1; gg < 8; ++gg) sm += red[gg * 64 + k];
    rsk[k] = 1.f / sm;
  }
  __syncthreads();
  const float rk = rsk[k];
  for (int n = g; n < Nn; n += 8) wt[n * 68 + k] *= rk;

  const int kg = tid >> 6, cg = tid & 63;
  float4 c0a = {0,0,0,0}, c0b = c0a, c1a = c0a, c1b = c0a;
  float4 c2a = c0a, c2b = c0a, c3a = c0a, c3b = c0a;
  float4 c4a = c0a, c4b = c0a, c5a = c0a, c5b = c0a;
  float4 c6a = c0a, c6b = c0a, c7a = c0a, c7b = c0a;

#pragma unroll 1
  for (int nt = 0; nt < 49; ++nt) {
    const int n0 = nt * 4;
    __syncthreads();
    {
      int row = tid >> 7, cf = tid & 127;
      float4 v = ld4s(x + ((size_t)(b * Nn + n0 + row)) * Dd + cf * 4);
      *(float4*)(xt + row * 512 + cf * 4) = v;
    }
    __syncthreads();
#pragma unroll 1
    for (int i = 0; i < 4; ++i) {
      const int n = n0 + i;
      const float4 wa = ld4s(wt + n * 68 + kg * 8);
      const float4 wb = ld4s(wt + n * 68 + kg * 8 + 4);
      const float4 xa = ld4s(xt + i * 512 + cg * 4);
      const float4 xb = ld4s(xt + i * 512 + 256 + cg * 4);
#define KSTEP(W, CA, CB) { \
      (CA).x += (W) * xa.x; (CA).y += (W) * xa.y; (CA).z += (W) * xa.z; (CA).w += (W) * xa.w; \
      (CB).x += (W) * xb.x; (CB).y += (W) * xb.y; (CB).z += (W) * xb.z; (CB).w += (W) * xb.w; }
      KSTEP(wa.x, c0a, c0b) KSTEP(wa.y, c1a, c1b)
      KSTEP(wa.z, c2a, c2b) KSTEP(wa.w, c3a, c3b)
      KSTEP(wb.x, c4a, c4b) KSTEP(wb.y, c5a, c5b)
      KSTEP(wb.z, c6a, c6b) KSTEP(wb.w, c7a, c7b)
#undef KSTEP
    }
  }
#define KOUT(KK, CA, CB) { \
  size_t base = ((size_t)((p * Bb + b) * Kk + kg * 8 + (KK))) * Dd; \
  *(float4*)(aggP + base + cg * 4) = CA; \
  *(float4*)(aggP + base + 256 + cg * 4) = CB; }
  KOUT(0, c0a, c0b) KOUT(1, c1a, c1b) KOUT(2, c2a, c2b) KOUT(3, c3a, c3b)
  KOUT(4, c4a, c4b) KOUT(5, c5a, c5b) KOUT(6, c6a, c6b) KOUT(7, c7a, c7b)
#undef KOUT
}

// ---------------------------------------------------------------------------
// K4 v2: per b, 512 threads (8 waves). v = agg_s+agg_d staged per 128-c chunk
// as vt[k][c] rows (512 B) with 16B-granule XOR swizzle (gc ^= k&31) so the
// 64-lane column read (lane = k) is conflict-free. Lane owns k = lane; wave w
// owns m = w*5..w*5+4. Dots accumulate in registers — no cross-lane ops in
// the hot loop. rnt via butterfly (all lanes), rnv via in-loop vsq.
// ---------------------------------------------------------------------------
__global__ __launch_bounds__(512) void k4_final(
    const float* __restrict__ words, const float* __restrict__ aggP,
    float* __restrict__ outp)
{
  __shared__ __align__(16) unsigned char vls[64 * 512];  // 32 KB swizzled vt
  __shared__ float rowm[40];
  __shared__ float colp[8][72];
  const int tid = threadIdx.x, b = blockIdx.x;
  const int w = tid >> 6, lane = tid & 63;
  const float* a0  = aggP + (size_t)b * (Kk * Dd);
  const float* a1  = aggP + ((size_t)(Bb + b)) * (Kk * Dd);
  const float* wrd = words + (size_t)b * Mm * Dd;
  const int m0 = w * 5;

  // rnt for this wave's 5 rows (butterfly sum -> all lanes)
  float rnt0, rnt1, rnt2, rnt3, rnt4;
#define TNORM(R, I) { \
    const float* tr = wrd + (size_t)(m0 + (I)) * Dd + lane * 8; \
    float4 ta = ld4s(tr), tb = ld4s(tr + 4); \
    float ss = wave_reduce_sum(dot4(ta, ta) + dot4(tb, tb)); \
    R = 1.f / fmaxf(sqrtf(ss), 1e-8f); }
  TNORM(rnt0, 0) TNORM(rnt1, 1) TNORM(rnt2, 2) TNORM(rnt3, 3) TNORM(rnt4, 4)
#undef TNORM

  float acc0 = 0.f, acc1 = 0.f, acc2 = 0.f, acc3 = 0.f, acc4 = 0.f, vsq = 0.f;

#pragma unroll 1
  for (int chn = 0; chn < 4; ++chn) {
    const int c0 = chn * 128;
    __syncthreads();
    // stage: 2048 granules (64 k x 32 gc), 4 per thread; coalesced reads,
    // row-contiguous swizzled writes
#pragma unroll
    for (int s = 0; s < 4; ++s) {
      const int idx = tid + s * 512;
      const int k = idx >> 5, gc = idx & 31;
      const float4 u = ld4s(a0 + (size_t)k * Dd + c0 + gc * 4);
      const float4 v = ld4s(a1 + (size_t)k * Dd + c0 + gc * 4);
      float4 sv = {u.x + v.x, u.y + v.y, u.z + v.z, u.w + v.w};
      *(float4*)(vls + k * 512 + ((gc ^ (k & 31)) << 4)) = sv;
    }
    __syncthreads();
    // compute: lane = k; 32 granule-iters over this chunk
#pragma unroll 2
    for (int cc = 0; cc < 32; ++cc) {
      const float4 vv = *(const float4*)(vls + lane * 512 + ((cc ^ (lane & 31)) << 4));
      const float* tp = wrd + c0 + cc * 4;
      const float4 t0 = ld4s(tp + (size_t)(m0    ) * Dd);
      const float4 t1 = ld4s(tp + (size_t)(m0 + 1) * Dd);
      const float4 t2 = ld4s(tp + (size_t)(m0 + 2) * Dd);
      const float4 t3 = ld4s(tp + (size_t)(m0 + 3) * Dd);
      const float4 t4 = ld4s(tp + (size_t)(m0 + 4) * Dd);
      acc0 += dot4(t0, vv); acc1 += dot4(t1, vv); acc2 += dot4(t2, vv);
      acc3 += dot4(t3, vv); acc4 += dot4(t4, vv);
      vsq  += dot4(vv, vv);
    }
  }

  // epilogue: normalize, leaky, pools
  const float rnv = 1.f / fmaxf(sqrtf(vsq), 1e-8f);
  float cmax = -1e30f;
#define DOM(ACC, RNT, I) { \
    float s = (ACC) * (RNT) * rnv; \
    s = (s >= 0.f) ? s : 0.1f * s; \
    cmax = fmaxf(cmax, s); \
    float rm = wave_reduce_max(s); \
    if (lane == 0) rowm[m0 + (I)] = rm; }
  DOM(acc0, rnt0, 0) DOM(acc1, rnt1, 1) DOM(acc2, rnt2, 2)
  DOM(acc3, rnt3, 3) DOM(acc4, rnt4, 4)
#undef DOM
  colp[w][lane] = cmax;
  __syncthreads();
  if (w == 0) {
    float cm = colp[0][lane];
#pragma unroll
    for (int ww = 1; ww < 8; ++ww) cm = fmaxf(cm, colp[ww][lane]);
    const float csum = wave_reduce_sum(cm);
    const float rv = (lane < 40) ? rowm[lane] : 0.f;
    const float rsum = wave_reduce_sum(rv);
    if (lane == 0) outp[b] = rsum * (1.f / 40.f) + csum * (1.f / 64.f);
  }
}

extern "C" void kernel_launch(void* const* d_in, const int* in_sizes, int n_in,
                              void* d_out, int out_size, void* d_ws, size_t ws_size,
                              hipStream_t stream)
{
  const float* x_s   = (const float*)d_in[0];
  const float* x_d   = (const float*)d_in[1];
  const float* words = (const float*)d_in[2];
  const float* g_s   = (const float*)d_in[3];
  const float* b_s   = (const float*)d_in[4];
  const float* w1_s  = (const float*)d_in[5];
  const float* b1_s  = (const float*)d_in[6];
  const float* w2_s  = (const float*)d_in[7];
  const float* b2_s  = (const float*)d_in[8];
  const float* g_d   = (const float*)d_in[9];
  const float* b_d   = (const float*)d_in[10];
  const float* w1_d  = (const float*)d_in[11];
  const float* b1_d  = (const float*)d_in[12];
  const float* w2_d  = (const float*)d_in[13];
  const float* b2_d  = (const float*)d_in[14];
  const float* scale = (const float*)d_in[15];
  (void)in_sizes; (void)n_in; (void)out_size; (void)ws_size;

  char* ws = (char*)d_ws;
  float* logits       = (float*)ws;
  unsigned short* w1h = (unsigned short*)(ws + W1H_OFF);
  unsigned short* w1l = (unsigned short*)(ws + W1L_OFF);
  float* gwb1         = (float*)(ws + GWB1_OFF);
  float* aggP         = (float*)(ws + AGG_OFF);

  hipLaunchKernelGGL(k0_wprep, dim3(2, 8), dim3(512), 0, stream,
                     g_s, b_s, w1_s, b1_s, g_d, b_d, w1_d, b1_d,
                     w1h, w1l, gwb1);
  hipLaunchKernelGGL(k1_logits, dim3(2, 2, 256), dim3(512), 0, stream,
                     x_s, x_d, w1h, w1l, gwb1,
                     w2_s, b2_s, w2_d, b2_d, logits);
  hipLaunchKernelGGL(k2_softmax_agg, dim3(2, 256), dim3(512), 0, stream,
                     x_s, x_d, logits, scale, aggP);
  hipLaunchKernelGGL(k4_final, dim3(256), dim3(512), 0, stream,
                     words, aggP, (float*)d_out);
}